// Round 1
// baseline (4847.137 us; speedup 1.0000x reference)
//
#include <hip/hip_runtime.h>

#define NN 8192
#define F0 512
#define F1 256
#define F2 16

// ---------------- d[i] = rsqrt(1 + rowsum(adj)) ----------------
__global__ __launch_bounds__(256) void k_rowsum(const float* __restrict__ adj,
                                                float* __restrict__ d) {
  __shared__ float red[256];
  const float4* row = (const float4*)(adj + (size_t)blockIdx.x * NN);
  float s = 0.f;
  for (int j = threadIdx.x; j < NN / 4; j += 256) {
    float4 v = row[j];
    s += (v.x + v.y) + (v.z + v.w);
  }
  red[threadIdx.x] = s;
  __syncthreads();
  for (int off = 128; off > 0; off >>= 1) {
    if (threadIdx.x < off) red[threadIdx.x] += red[threadIdx.x + off];
    __syncthreads();
  }
  if (threadIdx.x == 0) d[blockIdx.x] = rsqrtf(1.0f + red[0]);
}

// ---------------- rs_n[i] = d_i * sum_j adj[i][j] d_j + d_i^2 ----------------
__global__ __launch_bounds__(256) void k_wrowsum(const float* __restrict__ adj,
                                                 const float* __restrict__ d,
                                                 float* __restrict__ rs_n) {
  __shared__ float red[256];
  const float4* row = (const float4*)(adj + (size_t)blockIdx.x * NN);
  const float4* d4 = (const float4*)d;
  float s = 0.f;
  for (int j = threadIdx.x; j < NN / 4; j += 256) {
    float4 v = row[j];
    float4 w = d4[j];
    s += v.x * w.x + v.y * w.y + v.z * w.z + v.w * w.w;
  }
  red[threadIdx.x] = s;
  __syncthreads();
  for (int off = 128; off > 0; off >>= 1) {
    if (threadIdx.x < off) red[threadIdx.x] += red[threadIdx.x + off];
    __syncthreads();
  }
  if (threadIdx.x == 0) {
    float di = d[blockIdx.x];
    rs_n[blockIdx.x] = di * red[0] + di * di;
  }
}

// ---------------- cs_raw[j] += sum_i adj[i][j] d_i  (row-chunked, atomics) ----
__global__ __launch_bounds__(256) void k_colsum(const float* __restrict__ adj,
                                                const float* __restrict__ d,
                                                float* __restrict__ cs) {
  int j = blockIdx.x * 256 + threadIdx.x;
  int r0 = blockIdx.y * (NN / 64);
  int r1 = r0 + (NN / 64);
  float s = 0.f;
  for (int i = r0; i < r1; ++i) s += adj[(size_t)i * NN + j] * d[i];
  atomicAdd(&cs[j], s);
}

// ---------------- rowsum_sym, r_inv ----------------
__global__ __launch_bounds__(256) void k_finalize(const float* __restrict__ d,
                                                  const float* __restrict__ rs_n,
                                                  const float* __restrict__ cs_raw,
                                                  float* __restrict__ rssym,
                                                  float* __restrict__ rinv) {
  int i = blockIdx.x * 256 + threadIdx.x;
  float di = d[i];
  float cs_n = di * cs_raw[i] + di * di;
  float rs = 0.5f * (rs_n[i] + cs_n);
  rssym[i] = rs;
  rinv[i] = rsqrtf(rs + 0.001f);
}

// ---------------- big GEMMs against adj ----------------
// MODE 0: U[:, 0:512]  = adj_n @ x ; U[:, 512:1024] = adj_n @ (r_inv ⊙ x)
// MODE 1: V            = adj_n^T @ (r_inv ⊙ x)
// MODE 2: Uh           = adj_n @ H0       (src stride F1)
// Implicit B[k][j] = scale(k) * src[k][j]; epilogue y = d_i*acc + d_i^2 * srcscale(i)
template <int MODE>
__global__ __launch_bounds__(256) void big_gemm(const float* __restrict__ adj,
                                                const float* __restrict__ src,
                                                const float* __restrict__ d,
                                                const float* __restrict__ rinv,
                                                float* __restrict__ outp) {
  constexpr int BM = 128, BN = 128, BK = 8;
  __shared__ float As[BK][BM];
  __shared__ float Bs[BK][BN];
  const int i0 = blockIdx.x * BM;
  const int j0 = blockIdx.y * BN;
  const int t = threadIdx.x;
  const int tx = t & 15, ty = t >> 4;
  float acc[8][8] = {};

  for (int k0 = 0; k0 < NN; k0 += BK) {
    // --- A tile ---
    if (MODE == 1) {
      // A = adj^T : load adj[k][i] rows directly (already "transposed" layout)
      int ak = t >> 5, ai4 = (t & 31) * 4;
      float4 av = *(const float4*)(adj + (size_t)(k0 + ak) * NN + i0 + ai4);
      *(float4*)&As[ak][ai4] = av;
    } else {
      int ar = t >> 1, ac4 = (t & 1) * 4;
      float4 av = *(const float4*)(adj + (size_t)(i0 + ar) * NN + k0 + ac4);
      As[ac4 + 0][ar] = av.x;
      As[ac4 + 1][ar] = av.y;
      As[ac4 + 2][ar] = av.z;
      As[ac4 + 3][ar] = av.w;
    }
    // --- B tile (implicit, scaled) ---
    {
      int br = t >> 5, bc4 = (t & 31) * 4;
      int k = k0 + br;
      float scale;
      const float* bsrc;
      if (MODE == 0) {
        if (j0 < F0) {
          scale = d[k];
          bsrc = src + (size_t)k * F0 + j0 + bc4;
        } else {
          scale = d[k] * rinv[k];
          bsrc = src + (size_t)k * F0 + (j0 - F0) + bc4;
        }
      } else if (MODE == 1) {
        scale = d[k] * rinv[k];
        bsrc = src + (size_t)k * F0 + j0 + bc4;
      } else {
        scale = d[k];
        bsrc = src + (size_t)k * F1 + j0 + bc4;
      }
      float4 bv = *(const float4*)bsrc;
      bv.x *= scale; bv.y *= scale; bv.z *= scale; bv.w *= scale;
      *(float4*)&Bs[br][bc4] = bv;
    }
    __syncthreads();
#pragma unroll
    for (int k = 0; k < BK; ++k) {
      float a[8], b[8];
#pragma unroll
      for (int m = 0; m < 8; ++m) a[m] = As[k][ty * 8 + m];
#pragma unroll
      for (int n = 0; n < 8; ++n) b[n] = Bs[k][tx * 8 + n];
#pragma unroll
      for (int m = 0; m < 8; ++m)
#pragma unroll
        for (int n = 0; n < 8; ++n) acc[m][n] += a[m] * b[n];
    }
    __syncthreads();
  }

  // --- epilogue ---
#pragma unroll
  for (int m = 0; m < 8; ++m) {
    int i = i0 + ty * 8 + m;
    float di = d[i];
#pragma unroll
    for (int n = 0; n < 8; ++n) {
      int j = j0 + tx * 8 + n;
      float v = di * acc[m][n];
      if (MODE == 0) {
        if (j < F0)
          v += di * di * src[(size_t)i * F0 + j];
        else
          v += di * di * rinv[i] * src[(size_t)i * F0 + j - F0];
        outp[(size_t)i * 1024 + j] = v;
      } else if (MODE == 1) {
        v += di * di * rinv[i] * src[(size_t)i * F0 + j];
        outp[(size_t)i * F0 + j] = v;
      } else {
        v += di * di * src[(size_t)i * F1 + j];
        outp[(size_t)i * F1 + j] = v;
      }
    }
  }
}

// ---------------- H0 = relu(U[:, :512] @ W0) ----------------
__global__ __launch_bounds__(256) void k_h0(const float* __restrict__ U,
                                            const float* __restrict__ W0,
                                            float* __restrict__ H0) {
  constexpr int BM = 128, BN = 128, BK = 8;
  __shared__ float As[BK][BM];
  __shared__ float Bs[BK][BN];
  const int i0 = blockIdx.x * BM;
  const int j0 = blockIdx.y * BN;
  const int t = threadIdx.x;
  const int tx = t & 15, ty = t >> 4;
  float acc[8][8] = {};

  for (int k0 = 0; k0 < F0; k0 += BK) {
    {
      int ar = t >> 1, ac4 = (t & 1) * 4;
      float4 av = *(const float4*)(U + (size_t)(i0 + ar) * 1024 + k0 + ac4);
      As[ac4 + 0][ar] = av.x;
      As[ac4 + 1][ar] = av.y;
      As[ac4 + 2][ar] = av.z;
      As[ac4 + 3][ar] = av.w;
    }
    {
      int br = t >> 5, bc4 = (t & 31) * 4;
      float4 bv = *(const float4*)(W0 + (size_t)(k0 + br) * F1 + j0 + bc4);
      *(float4*)&Bs[br][bc4] = bv;
    }
    __syncthreads();
#pragma unroll
    for (int k = 0; k < BK; ++k) {
      float a[8], b[8];
#pragma unroll
      for (int m = 0; m < 8; ++m) a[m] = As[k][ty * 8 + m];
#pragma unroll
      for (int n = 0; n < 8; ++n) b[n] = Bs[k][tx * 8 + n];
#pragma unroll
      for (int m = 0; m < 8; ++m)
#pragma unroll
        for (int n = 0; n < 8; ++n) acc[m][n] += a[m] * b[n];
    }
    __syncthreads();
  }
#pragma unroll
  for (int m = 0; m < 8; ++m) {
    int i = i0 + ty * 8 + m;
#pragma unroll
    for (int n = 0; n < 8; ++n) {
      int j = j0 + tx * 8 + n;
      float v = acc[m][n];
      H0[(size_t)i * F1 + j] = v > 0.f ? v : 0.f;
    }
  }
}

// ---------------- out = Uh @ W1 ----------------
__global__ __launch_bounds__(256) void k_out(const float* __restrict__ Uh,
                                             const float* __restrict__ W1,
                                             float* __restrict__ outp) {
  __shared__ float W1s[F1 * F2];
  for (int idx = threadIdx.x; idx < F1 * F2; idx += 256) W1s[idx] = W1[idx];
  __syncthreads();
  int r = threadIdx.x >> 4, f = threadIdx.x & 15;
  int i = blockIdx.x * 16 + r;
  const float* urow = Uh + (size_t)i * F1;
  float acc = 0.f;
#pragma unroll 8
  for (int k = 0; k < F1; ++k) acc += urow[k] * W1s[k * F2 + f];
  outp[(size_t)i * F2 + f] = acc;
}

// ---------------- loss reduction ----------------
__global__ __launch_bounds__(256) void k_loss(const float* __restrict__ x,
                                              const float* __restrict__ U,
                                              const float* __restrict__ V,
                                              const float* __restrict__ rssym,
                                              const float* __restrict__ rinv,
                                              float* __restrict__ loss) {
  __shared__ float red[256];
  float s = 0.f;
  size_t total = (size_t)NN * F0;
  for (size_t idx = (size_t)blockIdx.x * 256 + threadIdx.x; idx < total;
       idx += (size_t)gridDim.x * 256) {
    int i = (int)(idx >> 9);
    int j = (int)(idx & 511);
    float xv = x[idx];
    float ri = rinv[i];
    float Y = ri * xv;
    float LY = rssym[i] * Y - 0.5f * (U[(size_t)i * 1024 + F0 + j] + V[idx]);
    s += xv * ri * LY;
  }
  red[threadIdx.x] = s;
  __syncthreads();
  for (int off = 128; off > 0; off >>= 1) {
    if (threadIdx.x < off) red[threadIdx.x] += red[threadIdx.x + off];
    __syncthreads();
  }
  if (threadIdx.x == 0) atomicAdd(loss, red[0]);
}

extern "C" void kernel_launch(void* const* d_in, const int* in_sizes, int n_in,
                              void* d_out, int out_size, void* d_ws, size_t ws_size,
                              hipStream_t stream) {
  const float* x = (const float*)d_in[0];
  const float* adj = (const float*)d_in[1];
  // d_in[2], d_in[3] are mask1/mask2 == (adj != 0); adj*mask1*mask2 == adj exactly, skip.
  const float* W0 = (const float*)d_in[4];
  const float* W1 = (const float*)d_in[5];
  float* out = (float*)d_out;

  float* ws = (float*)d_ws;
  float* d_v = ws;                         // N
  float* rs_n = ws + 8192;                 // N
  float* cs = ws + 16384;                  // N (raw colsum)
  float* rssym = ws + 24576;               // N
  float* rinv = ws + 32768;                // N
  float* U = ws + 65536;                   // N*1024  [adj_n@x | adj_n@Y]
  float* V = U + (size_t)NN * 1024;        // N*512   adj_n^T@Y
  float* H0 = V + (size_t)NN * F0;         // N*256
  float* Uh = H0 + (size_t)NN * F1;        // N*256

  hipMemsetAsync(cs, 0, NN * sizeof(float), stream);
  hipMemsetAsync(out + (size_t)NN * F2, 0, sizeof(float), stream);

  k_rowsum<<<NN, 256, 0, stream>>>(adj, d_v);
  k_wrowsum<<<NN, 256, 0, stream>>>(adj, d_v, rs_n);
  k_colsum<<<dim3(NN / 256, 64), 256, 0, stream>>>(adj, d_v, cs);
  k_finalize<<<NN / 256, 256, 0, stream>>>(d_v, rs_n, cs, rssym, rinv);

  big_gemm<0><<<dim3(NN / 128, 1024 / 128), 256, 0, stream>>>(adj, x, d_v, rinv, U);
  big_gemm<1><<<dim3(NN / 128, F0 / 128), 256, 0, stream>>>(adj, x, d_v, rinv, V);
  k_loss<<<2048, 256, 0, stream>>>(x, U, V, rssym, rinv, out + (size_t)NN * F2);

  k_h0<<<dim3(NN / 128, F1 / 128), 256, 0, stream>>>(U, W0, H0);
  big_gemm<2><<<dim3(NN / 128, F1 / 128), 256, 0, stream>>>(adj, H0, d_v, rinv, Uh);
  k_out<<<NN / 16, 256, 0, stream>>>(Uh, W1, out);
}

// Round 2
// 550.743 us; speedup vs baseline: 8.8011x; 8.8011x over previous
//
#include <hip/hip_runtime.h>

#define NN 8192
#define F0 512
#define F1 256
#define F2 16

typedef __attribute__((ext_vector_type(8))) short bf16x8;
typedef __attribute__((ext_vector_type(4))) float f32x4;

__device__ __forceinline__ ushort f2bf(float f) {
  unsigned u = __float_as_uint(f);
  u += 0x7FFFu + ((u >> 16) & 1u);   // RNE
  return (ushort)(u >> 16);
}
__device__ __forceinline__ float bf2f(ushort u) {
  return __uint_as_float(((unsigned)u) << 16);
}
__device__ __forceinline__ void gload_lds16(const void* g, void* l) {
  __builtin_amdgcn_global_load_lds((const __attribute__((address_space(1))) void*)g,
                                   (__attribute__((address_space(3))) void*)l, 16, 0, 0);
}

// ---------- pass1: rowsum (fp32, exact) + adj -> bf16 convert ----------
__global__ __launch_bounds__(256) void k_pass1(const float* __restrict__ adj,
                                               ushort* __restrict__ adjb,
                                               float* __restrict__ d) {
  __shared__ float red[256];
  const size_t base = (size_t)blockIdx.x * NN;
  float s = 0.f;
  for (int j = threadIdx.x * 4; j < NN; j += 1024) {
    float4 v = *(const float4*)&adj[base + j];
    s += (v.x + v.y) + (v.z + v.w);
    ushort4 o;
    o.x = f2bf(v.x); o.y = f2bf(v.y); o.z = f2bf(v.z); o.w = f2bf(v.w);
    *(ushort4*)&adjb[base + j] = o;
  }
  red[threadIdx.x] = s;
  __syncthreads();
  for (int off = 128; off > 0; off >>= 1) {
    if (threadIdx.x < off) red[threadIdx.x] += red[threadIdx.x + off];
    __syncthreads();
  }
  if (threadIdx.x == 0) d[blockIdx.x] = rsqrtf(1.0f + red[0]);
}

// ---------- rs_n[i] = d_i * sum_j adjb[i][j] d_j + d_i^2 ----------
__global__ __launch_bounds__(256) void k_wrowsum(const ushort* __restrict__ adjb,
                                                 const float* __restrict__ d,
                                                 float* __restrict__ rs_n) {
  __shared__ float red[256];
  const uint4* row = (const uint4*)(adjb + (size_t)blockIdx.x * NN);
  float s = 0.f;
  for (int p = threadIdx.x; p < NN / 8; p += 256) {
    uint4 pk = row[p];
    float4 d0 = *(const float4*)&d[p * 8];
    float4 d1 = *(const float4*)&d[p * 8 + 4];
    s += bf2f((ushort)(pk.x & 0xffff)) * d0.x + bf2f((ushort)(pk.x >> 16)) * d0.y
       + bf2f((ushort)(pk.y & 0xffff)) * d0.z + bf2f((ushort)(pk.y >> 16)) * d0.w
       + bf2f((ushort)(pk.z & 0xffff)) * d1.x + bf2f((ushort)(pk.z >> 16)) * d1.y
       + bf2f((ushort)(pk.w & 0xffff)) * d1.z + bf2f((ushort)(pk.w >> 16)) * d1.w;
  }
  red[threadIdx.x] = s;
  __syncthreads();
  for (int off = 128; off > 0; off >>= 1) {
    if (threadIdx.x < off) red[threadIdx.x] += red[threadIdx.x + off];
    __syncthreads();
  }
  if (threadIdx.x == 0) {
    float di = d[blockIdx.x];
    rs_n[blockIdx.x] = di * red[0] + di * di;
  }
}

// ---------- cs_raw[j] += sum_i adjb[i][j] d_i ----------
__global__ __launch_bounds__(256) void k_colsum(const ushort* __restrict__ adjb,
                                                const float* __restrict__ d,
                                                float* __restrict__ cs) {
  int j = blockIdx.x * 256 + threadIdx.x;
  int r0 = blockIdx.y * 128;
  float s = 0.f;
  for (int i = r0; i < r0 + 128; ++i) s += bf2f(adjb[(size_t)i * NN + j]) * d[i];
  atomicAdd(&cs[j], s);
}

__global__ __launch_bounds__(256) void k_finalize(const float* __restrict__ d,
                                                  const float* __restrict__ rs_n,
                                                  const float* __restrict__ cs_raw,
                                                  float* __restrict__ rssym,
                                                  float* __restrict__ rinv) {
  int i = blockIdx.x * 256 + threadIdx.x;
  float di = d[i];
  float cs_n = di * cs_raw[i] + di * di;
  float rs = 0.5f * (rs_n[i] + cs_n);
  rssym[i] = rs;
  rinv[i] = rsqrtf(rs + 0.001f);
}

// ---------- BxT[j][k] = bf16(d_k x[k][j]);  BxT[512+j][k] = bf16(d_k rinv_k x[k][j]) ----------
__global__ __launch_bounds__(256) void k_buildBxT(const float* __restrict__ x,
                                                  const float* __restrict__ d,
                                                  const float* __restrict__ rinv,
                                                  ushort* __restrict__ BxT) {
  __shared__ float tile[64][65];
  const int k0 = blockIdx.x * 64, j0 = blockIdx.y * 64;
  const int tc = threadIdx.x & 15, tr = threadIdx.x >> 4;
#pragma unroll
  for (int it = 0; it < 4; ++it) {
    int r = tr + it * 16;
    float4 v = *(const float4*)&x[(size_t)(k0 + r) * F0 + j0 + tc * 4];
    tile[r][tc * 4 + 0] = v.x; tile[r][tc * 4 + 1] = v.y;
    tile[r][tc * 4 + 2] = v.z; tile[r][tc * 4 + 3] = v.w;
  }
  __syncthreads();
#pragma unroll
  for (int it = 0; it < 4; ++it) {
    int j = tr + it * 16;
    int kk = tc * 4;
    ushort4 o0, o1;
#pragma unroll
    for (int q = 0; q < 4; ++q) {
      int k = k0 + kk + q;
      float val = tile[kk + q][j];
      ((ushort*)&o0)[q] = f2bf(d[k] * val);
      ((ushort*)&o1)[q] = f2bf(d[k] * rinv[k] * val);
    }
    *(ushort4*)&BxT[(size_t)(j0 + j) * NN + k0 + kk] = o0;
    *(ushort4*)&BxT[(size_t)(F0 + j0 + j) * NN + k0 + kk] = o1;
  }
}

// ---------- W0T[j][k] = bf16(W0[k][j]) ----------
__global__ __launch_bounds__(256) void k_buildW0T(const float* __restrict__ W0,
                                                  ushort* __restrict__ W0T) {
  __shared__ float tile[64][65];
  const int k0 = blockIdx.x * 64, j0 = blockIdx.y * 64;
  const int tc = threadIdx.x & 15, tr = threadIdx.x >> 4;
#pragma unroll
  for (int it = 0; it < 4; ++it) {
    int r = tr + it * 16;
    float4 v = *(const float4*)&W0[(size_t)(k0 + r) * F1 + j0 + tc * 4];
    tile[r][tc * 4 + 0] = v.x; tile[r][tc * 4 + 1] = v.y;
    tile[r][tc * 4 + 2] = v.z; tile[r][tc * 4 + 3] = v.w;
  }
  __syncthreads();
#pragma unroll
  for (int it = 0; it < 4; ++it) {
    int j = tr + it * 16;
    int kk = tc * 4;
    ushort4 o;
#pragma unroll
    for (int q = 0; q < 4; ++q) ((ushort*)&o)[q] = f2bf(tile[kk + q][j]);
    *(ushort4*)&W0T[(size_t)(j0 + j) * F0 + k0 + kk] = o;
  }
}

// ---------- MFMA GEMM: C = A(MxK bf16,row-major) @ B^T(NxK bf16,row-major) ----------
// MODE 0: A=adjb K=8192, B=BxT; j<512: U1b=bf16(d*acc + d^2*x); j>=512: U2=d*acc + d^2*rinv*x
// MODE 1: A=U1b K=512,  B=W0T; H0=relu(acc) fp32, H0bT[j][i]=bf16(d_i*relu)
// MODE 2: A=adjb K=8192, B=H0bT; Uh = d*acc + d^2*H0
template <int MODE>
__global__ __launch_bounds__(256) void mfma_gemm(
    const ushort* __restrict__ A, int lda,
    const ushort* __restrict__ B, int ldb, int K,
    const float* __restrict__ d, const float* __restrict__ rinv,
    const float* __restrict__ aux, void* __restrict__ out1, void* __restrict__ out2) {
  __shared__ ushort As[128 * 32];
  __shared__ ushort Bs[128 * 32];
  const int i0 = blockIdx.x * 128, j0 = blockIdx.y * 128;
  const int t = threadIdx.x;
  const int lane = t & 63, w = t >> 6;
  const int wr = w >> 1, wc = w & 1;

  f32x4 acc[4][4] = {};

  const int e0 = t, e1 = t + 256;
  const ushort* ag0 = A + (size_t)(i0 + (e0 >> 2)) * lda + (e0 & 3) * 8;
  const ushort* ag1 = A + (size_t)(i0 + (e1 >> 2)) * lda + (e1 & 3) * 8;
  const ushort* bg0 = B + (size_t)(j0 + (e0 >> 2)) * ldb + (e0 & 3) * 8;
  const ushort* bg1 = B + (size_t)(j0 + (e1 >> 2)) * ldb + (e1 & 3) * 8;
  ushort* la0 = &As[w * 512];
  ushort* la1 = &As[2048 + w * 512];
  ushort* lb0 = &Bs[w * 512];
  ushort* lb1 = &Bs[2048 + w * 512];

  const int abase = (wr * 64 + (lane & 15)) * 32 + (lane >> 4) * 8;
  const int bbase = (wc * 64 + (lane & 15)) * 32 + (lane >> 4) * 8;

  for (int k0 = 0; k0 < K; k0 += 32) {
    gload_lds16(ag0 + k0, la0);
    gload_lds16(ag1 + k0, la1);
    gload_lds16(bg0 + k0, lb0);
    gload_lds16(bg1 + k0, lb1);
    __syncthreads();
    bf16x8 af[4], bfr[4];
#pragma unroll
    for (int m = 0; m < 4; ++m) af[m] = *(const bf16x8*)&As[abase + m * 512];
#pragma unroll
    for (int n = 0; n < 4; ++n) bfr[n] = *(const bf16x8*)&Bs[bbase + n * 512];
#pragma unroll
    for (int m = 0; m < 4; ++m)
#pragma unroll
      for (int n = 0; n < 4; ++n)
        acc[m][n] = __builtin_amdgcn_mfma_f32_16x16x32_bf16(af[m], bfr[n], acc[m][n], 0, 0, 0);
    __syncthreads();
  }

#pragma unroll
  for (int m = 0; m < 4; ++m) {
    const int rb = i0 + wr * 64 + m * 16 + (lane >> 4) * 4;
#pragma unroll
    for (int n = 0; n < 4; ++n) {
      const int j = j0 + wc * 64 + n * 16 + (lane & 15);
      f32x4 v = acc[m][n];
      if (MODE == 0) {
        if (j < F0) {
          ushort* U1b = (ushort*)out1;
#pragma unroll
          for (int q = 0; q < 4; ++q) {
            int r = rb + q;
            float dr = d[r];
            U1b[(size_t)r * F0 + j] = f2bf(dr * v[q] + dr * dr * aux[(size_t)r * F0 + j]);
          }
        } else {
          float* U2 = (float*)out2;
          int jj = j - F0;
#pragma unroll
          for (int q = 0; q < 4; ++q) {
            int r = rb + q;
            float dr = d[r];
            U2[(size_t)r * F0 + jj] = dr * v[q] + dr * dr * rinv[r] * aux[(size_t)r * F0 + jj];
          }
        }
      } else if (MODE == 1) {
        float* H0 = (float*)out1;
        ushort* H0bT = (ushort*)out2;
        ushort4 o;
#pragma unroll
        for (int q = 0; q < 4; ++q) {
          int r = rb + q;
          float hv = v[q] > 0.f ? v[q] : 0.f;
          H0[(size_t)r * F1 + j] = hv;
          ((ushort*)&o)[q] = f2bf(d[r] * hv);
        }
        *(ushort4*)&H0bT[(size_t)j * NN + rb] = o;
      } else {
        float* Uh = (float*)out1;
#pragma unroll
        for (int q = 0; q < 4; ++q) {
          int r = rb + q;
          float dr = d[r];
          Uh[(size_t)r * F1 + j] = dr * v[q] + dr * dr * aux[(size_t)r * F1 + j];
        }
      }
    }
  }
}

// ---------- loss = sum( Y * (rowsum_i * Y - U2) ), Y = rinv_i * x ----------
__global__ __launch_bounds__(256) void k_loss(const float* __restrict__ x,
                                              const float* __restrict__ U2,
                                              const float* __restrict__ rssym,
                                              const float* __restrict__ rinv,
                                              float* __restrict__ loss) {
  __shared__ float red[256];
  float s = 0.f;
  size_t total = (size_t)NN * F0;
  for (size_t idx = (size_t)blockIdx.x * 256 + threadIdx.x; idx < total;
       idx += (size_t)gridDim.x * 256) {
    int i = (int)(idx >> 9);
    float xv = x[idx];
    float Y = rinv[i] * xv;
    s += Y * (rssym[i] * Y - U2[idx]);
  }
  red[threadIdx.x] = s;
  __syncthreads();
  for (int off = 128; off > 0; off >>= 1) {
    if (threadIdx.x < off) red[threadIdx.x] += red[threadIdx.x + off];
    __syncthreads();
  }
  if (threadIdx.x == 0) atomicAdd(loss, red[0]);
}

// ---------- out = Uh @ W1 ----------
__global__ __launch_bounds__(256) void k_out(const float* __restrict__ Uh,
                                             const float* __restrict__ W1,
                                             float* __restrict__ outp) {
  __shared__ float W1s[F1 * F2];
  for (int idx = threadIdx.x; idx < F1 * F2; idx += 256) W1s[idx] = W1[idx];
  __syncthreads();
  int r = threadIdx.x >> 4, f = threadIdx.x & 15;
  int i = blockIdx.x * 16 + r;
  const float* urow = Uh + (size_t)i * F1;
  float acc = 0.f;
#pragma unroll 8
  for (int k = 0; k < F1; ++k) acc += urow[k] * W1s[k * F2 + f];
  outp[(size_t)i * F2 + f] = acc;
}

extern "C" void kernel_launch(void* const* d_in, const int* in_sizes, int n_in,
                              void* d_out, int out_size, void* d_ws, size_t ws_size,
                              hipStream_t stream) {
  const float* x = (const float*)d_in[0];
  const float* adj = (const float*)d_in[1];
  const float* W0 = (const float*)d_in[4];
  const float* W1 = (const float*)d_in[5];
  float* out = (float*)d_out;

  float* ws = (float*)d_ws;
  float* d_v = ws;                                   // 8192
  float* rs_n = ws + 8192;                           // 8192
  float* cs = ws + 16384;                            // 8192
  float* rssym = ws + 24576;                         // 8192
  float* rinv = ws + 32768;                          // 8192
  ushort* adjb = (ushort*)(ws + 65536);              // 8192*8192 bf16
  float* p = ws + 65536 + (size_t)NN * NN / 2;
  ushort* BxT = (ushort*)p;                          // 1024*8192 bf16
  p += (size_t)1024 * NN / 2;
  ushort* W0T = (ushort*)p;                          // 256*512 bf16
  p += (size_t)F1 * F0 / 2;
  ushort* U1b = (ushort*)p;                          // 8192*512 bf16
  p += (size_t)NN * F0 / 2;
  float* U2 = p;                                     // 8192*512 fp32
  p += (size_t)NN * F0;
  float* H0 = p;                                     // 8192*256 fp32
  p += (size_t)NN * F1;
  ushort* H0bT = (ushort*)p;                         // 256*8192 bf16
  p += (size_t)F1 * NN / 2;
  float* Uh = p;                                     // 8192*256 fp32

  hipMemsetAsync(cs, 0, NN * sizeof(float), stream);
  hipMemsetAsync(out + (size_t)NN * F2, 0, sizeof(float), stream);

  k_pass1<<<NN, 256, 0, stream>>>(adj, adjb, d_v);
  k_wrowsum<<<NN, 256, 0, stream>>>(adjb, d_v, rs_n);
  k_colsum<<<dim3(NN / 256, 64), 256, 0, stream>>>(adjb, d_v, cs);
  k_finalize<<<NN / 256, 256, 0, stream>>>(d_v, rs_n, cs, rssym, rinv);

  k_buildBxT<<<dim3(NN / 64, F0 / 64), 256, 0, stream>>>(x, d_v, rinv, BxT);
  k_buildW0T<<<dim3(F0 / 64, F1 / 64), 256, 0, stream>>>(W0, W0T);

  // layer-0 aggregation + smoothing numerator in one GEMM (N=1024)
  mfma_gemm<0><<<dim3(NN / 128, 1024 / 128), 256, 0, stream>>>(
      adjb, NN, BxT, NN, NN, d_v, rinv, x, U1b, U2);
  k_loss<<<2048, 256, 0, stream>>>(x, U2, rssym, rinv, out + (size_t)NN * F2);

  // H0 = relu(U1 @ W0)
  mfma_gemm<1><<<dim3(NN / 128, F1 / 128), 256, 0, stream>>>(
      U1b, F0, W0T, F0, F0, d_v, rinv, nullptr, H0, H0bT);

  // Uh = adj_n @ H0
  mfma_gemm<2><<<dim3(NN / 128, F1 / 128), 256, 0, stream>>>(
      adjb, NN, H0bT, NN, NN, d_v, rinv, H0, Uh, nullptr);

  k_out<<<NN / 16, 256, 0, stream>>>(Uh, W1, out);
}

// Round 3
// 510.892 us; speedup vs baseline: 9.4876x; 1.0780x over previous
//
#include <hip/hip_runtime.h>

#define NN 8192
#define F0 512
#define F1 256
#define F2 16

typedef __attribute__((ext_vector_type(8))) short bf16x8;
typedef __attribute__((ext_vector_type(4))) float f32x4;

__device__ __forceinline__ ushort f2bf(float f) {
  unsigned u = __float_as_uint(f);
  u += 0x7FFFu + ((u >> 16) & 1u);  // RNE
  return (ushort)(u >> 16);
}
__device__ __forceinline__ float bf2f(ushort u) {
  return __uint_as_float(((unsigned)u) << 16);
}
__device__ __forceinline__ void unpack8(uint4 a, float* f) {
  f[0] = bf2f((ushort)(a.x & 0xffff)); f[1] = bf2f((ushort)(a.x >> 16));
  f[2] = bf2f((ushort)(a.y & 0xffff)); f[3] = bf2f((ushort)(a.y >> 16));
  f[4] = bf2f((ushort)(a.z & 0xffff)); f[5] = bf2f((ushort)(a.z >> 16));
  f[6] = bf2f((ushort)(a.w & 0xffff)); f[7] = bf2f((ushort)(a.w >> 16));
}
__device__ __forceinline__ void gload_lds16(const void* g, void* l) {
  __builtin_amdgcn_global_load_lds((const __attribute__((address_space(1))) void*)g,
                                   (__attribute__((address_space(3))) void*)l, 16, 0, 0);
}

// ---------- pass1: rowsum (fp32 exact) + adj -> bf16 ----------
__global__ __launch_bounds__(256) void k_pass1(const float* __restrict__ adj,
                                               ushort* __restrict__ adjb,
                                               float* __restrict__ d) {
  __shared__ float red[256];
  const size_t base = (size_t)blockIdx.x * NN;
  float s = 0.f;
  for (int j = threadIdx.x * 4; j < NN; j += 1024) {
    float4 v = *(const float4*)&adj[base + j];
    s += (v.x + v.y) + (v.z + v.w);
    ushort4 o;
    o.x = f2bf(v.x); o.y = f2bf(v.y); o.z = f2bf(v.z); o.w = f2bf(v.w);
    *(ushort4*)&adjb[base + j] = o;
  }
  red[threadIdx.x] = s;
  __syncthreads();
  for (int off = 128; off > 0; off >>= 1) {
    if (threadIdx.x < off) red[threadIdx.x] += red[threadIdx.x + off];
    __syncthreads();
  }
  if (threadIdx.x == 0) d[blockIdx.x] = rsqrtf(1.0f + red[0]);
}

// ---------- rs_n[i] = d_i * sum_j adjb[i][j] d_j + d_i^2 ----------
__global__ __launch_bounds__(256) void k_wrowsum(const ushort* __restrict__ adjb,
                                                 const float* __restrict__ d,
                                                 float* __restrict__ rs_n) {
  __shared__ float red[256];
  float s = 0.f;
  for (int p = threadIdx.x; p < NN / 8; p += 256) {
    uint4 pk = *(const uint4*)&adjb[(size_t)blockIdx.x * NN + p * 8];
    float t[8]; unpack8(pk, t);
    const float4 d0 = *(const float4*)&d[p * 8];
    const float4 d1 = *(const float4*)&d[p * 8 + 4];
    s += t[0] * d0.x + t[1] * d0.y + t[2] * d0.z + t[3] * d0.w
       + t[4] * d1.x + t[5] * d1.y + t[6] * d1.z + t[7] * d1.w;
  }
  red[threadIdx.x] = s;
  __syncthreads();
  for (int off = 128; off > 0; off >>= 1) {
    if (threadIdx.x < off) red[threadIdx.x] += red[threadIdx.x + off];
    __syncthreads();
  }
  if (threadIdx.x == 0) {
    float di = d[blockIdx.x];
    rs_n[blockIdx.x] = di * red[0] + di * di;
  }
}

// ---------- cs_raw[c] += sum_i adjb[i][c] d_i ----------
__global__ __launch_bounds__(256) void k_colsum(const ushort* __restrict__ adjb,
                                                const float* __restrict__ d,
                                                float* __restrict__ cs) {
  const int c0 = blockIdx.x * 2048 + threadIdx.x * 8;
  const int r0 = blockIdx.y * 128;
  float acc[8] = {};
  for (int i = 0; i < 128; ++i) {
    uint4 v = *(const uint4*)&adjb[(size_t)(r0 + i) * NN + c0];
    float t[8]; unpack8(v, t);
    float di = d[r0 + i];
#pragma unroll
    for (int q = 0; q < 8; ++q) acc[q] += t[q] * di;
  }
#pragma unroll
  for (int q = 0; q < 8; ++q) atomicAdd(&cs[c0 + q], acc[q]);
}

__global__ __launch_bounds__(256) void k_finalize(const float* __restrict__ d,
                                                  const float* __restrict__ rs_n,
                                                  const float* __restrict__ cs_raw,
                                                  float* __restrict__ rinv,
                                                  float* __restrict__ wbuf) {
  int i = blockIdx.x * 256 + threadIdx.x;
  float di = d[i];
  float cs_n = di * cs_raw[i] + di * di;
  float rs = 0.5f * (rs_n[i] + cs_n);
  rinv[i] = rsqrtf(rs + 0.001f);
  wbuf[i] = rs / (rs + 0.001f);  // rssym * rinv^2
}

// ---------- BxT build + loss term A = sum_i w_i * |x_i|^2 ----------
__global__ __launch_bounds__(256) void k_buildBxT(const float* __restrict__ x,
                                                  const float* __restrict__ d,
                                                  const float* __restrict__ rinv,
                                                  const float* __restrict__ wbuf,
                                                  ushort* __restrict__ BxT,
                                                  float* __restrict__ loss) {
  __shared__ float tile[64][65];
  __shared__ float red[256];
  const int k0 = blockIdx.x * 64, j0 = blockIdx.y * 64;
  const int tc = threadIdx.x & 15, tr = threadIdx.x >> 4;
  float s = 0.f;
#pragma unroll
  for (int it = 0; it < 4; ++it) {
    int r = tr + it * 16;
    float4 v = *(const float4*)&x[(size_t)(k0 + r) * F0 + j0 + tc * 4];
    s += wbuf[k0 + r] * (v.x * v.x + v.y * v.y + v.z * v.z + v.w * v.w);
    tile[r][tc * 4 + 0] = v.x; tile[r][tc * 4 + 1] = v.y;
    tile[r][tc * 4 + 2] = v.z; tile[r][tc * 4 + 3] = v.w;
  }
  red[threadIdx.x] = s;
  __syncthreads();
#pragma unroll
  for (int it = 0; it < 4; ++it) {
    int j = tr + it * 16;
    int kk = tc * 4;
    ushort4 o0, o1;
#pragma unroll
    for (int q = 0; q < 4; ++q) {
      int k = k0 + kk + q;
      float val = tile[kk + q][j];
      ((ushort*)&o0)[q] = f2bf(d[k] * val);
      ((ushort*)&o1)[q] = f2bf(d[k] * rinv[k] * val);
    }
    *(ushort4*)&BxT[(size_t)(j0 + j) * NN + k0 + kk] = o0;
    *(ushort4*)&BxT[(size_t)(F0 + j0 + j) * NN + k0 + kk] = o1;
  }
  __syncthreads();
  for (int off = 128; off > 0; off >>= 1) {
    if (threadIdx.x < off) red[threadIdx.x] += red[threadIdx.x + off];
    __syncthreads();
  }
  if (threadIdx.x == 0) atomicAdd(loss, red[0]);
}

// ---------- W0T[j][k] = bf16(W0[k][j]) ----------
__global__ __launch_bounds__(256) void k_buildW0T(const float* __restrict__ W0,
                                                  ushort* __restrict__ W0T) {
  __shared__ float tile[64][65];
  const int k0 = blockIdx.x * 64, j0 = blockIdx.y * 64;
  const int tc = threadIdx.x & 15, tr = threadIdx.x >> 4;
#pragma unroll
  for (int it = 0; it < 4; ++it) {
    int r = tr + it * 16;
    float4 v = *(const float4*)&W0[(size_t)(k0 + r) * F1 + j0 + tc * 4];
    tile[r][tc * 4 + 0] = v.x; tile[r][tc * 4 + 1] = v.y;
    tile[r][tc * 4 + 2] = v.z; tile[r][tc * 4 + 3] = v.w;
  }
  __syncthreads();
#pragma unroll
  for (int it = 0; it < 4; ++it) {
    int j = tr + it * 16;
    int kk = tc * 4;
    ushort4 o;
#pragma unroll
    for (int q = 0; q < 4; ++q) ((ushort*)&o)[q] = f2bf(tile[kk + q][j]);
    *(ushort4*)&W0T[(size_t)(j0 + j) * F0 + k0 + kk] = o;
  }
}

// ---------- split-K MFMA GEMM partial: Pk = A[:,kspan]@B^T[:,kspan], bf16 out ----------
__global__ __launch_bounds__(256) void k_gemm_part(
    const ushort* __restrict__ A, int lda,
    const ushort* __restrict__ B, int ldb,
    int kspan, ushort* __restrict__ P, int ldn) {
  __shared__ ushort As[128 * 32];
  __shared__ ushort Bs[128 * 32];
  const int i0 = blockIdx.x * 128, j0 = blockIdx.y * 128;
  const size_t kbase = (size_t)blockIdx.z * kspan;
  const int t = threadIdx.x;
  const int lane = t & 63, w = t >> 6;
  const int wr = w >> 1, wc = w & 1;

  f32x4 acc[4][4] = {};

  const int e0 = t, e1 = t + 256;
  const ushort* ag0 = A + (size_t)(i0 + (e0 >> 2)) * lda + (e0 & 3) * 8 + kbase;
  const ushort* ag1 = A + (size_t)(i0 + (e1 >> 2)) * lda + (e1 & 3) * 8 + kbase;
  const ushort* bg0 = B + (size_t)(j0 + (e0 >> 2)) * ldb + (e0 & 3) * 8 + kbase;
  const ushort* bg1 = B + (size_t)(j0 + (e1 >> 2)) * ldb + (e1 & 3) * 8 + kbase;
  ushort* la0 = &As[w * 512];
  ushort* la1 = &As[2048 + w * 512];
  ushort* lb0 = &Bs[w * 512];
  ushort* lb1 = &Bs[2048 + w * 512];

  const int abase = (wr * 64 + (lane & 15)) * 32 + (lane >> 4) * 8;
  const int bbase = (wc * 64 + (lane & 15)) * 32 + (lane >> 4) * 8;

  for (int k0 = 0; k0 < kspan; k0 += 32) {
    gload_lds16(ag0 + k0, la0);
    gload_lds16(ag1 + k0, la1);
    gload_lds16(bg0 + k0, lb0);
    gload_lds16(bg1 + k0, lb1);
    __syncthreads();
    bf16x8 af[4], bfr[4];
#pragma unroll
    for (int m = 0; m < 4; ++m) af[m] = *(const bf16x8*)&As[abase + m * 512];
#pragma unroll
    for (int n = 0; n < 4; ++n) bfr[n] = *(const bf16x8*)&Bs[bbase + n * 512];
#pragma unroll
    for (int m = 0; m < 4; ++m)
#pragma unroll
      for (int n = 0; n < 4; ++n)
        acc[m][n] = __builtin_amdgcn_mfma_f32_16x16x32_bf16(af[m], bfr[n], acc[m][n], 0, 0, 0);
    __syncthreads();
  }

  ushort* Pk = P + (size_t)blockIdx.z * NN * ldn;
#pragma unroll
  for (int m = 0; m < 4; ++m) {
    const int rb = i0 + wr * 64 + m * 16 + (lane >> 4) * 4;
#pragma unroll
    for (int n = 0; n < 4; ++n) {
      const int j = j0 + wc * 64 + n * 16 + (lane & 15);
      f32x4 v = acc[m][n];
#pragma unroll
      for (int q = 0; q < 4; ++q) Pk[(size_t)(rb + q) * ldn + j] = f2bf(v[q]);
    }
  }
}

// ---------- combine mode-0 partials: U1b epilogue + loss term B ----------
__global__ __launch_bounds__(256) void k_combine0(const ushort* __restrict__ P,
                                                  const float* __restrict__ x,
                                                  const float* __restrict__ d,
                                                  const float* __restrict__ rinv,
                                                  ushort* __restrict__ U1b,
                                                  float* __restrict__ loss) {
  __shared__ float red[256];
  float ls = 0.f;
  const int total = NN * 1024 / 8;
  for (int idx = blockIdx.x * 256 + threadIdx.x; idx < total; idx += gridDim.x * 256) {
    const int r = idx >> 7;
    const int c8 = idx & 127;
    uint4 p0 = *(const uint4*)&P[(size_t)r * 1024 + c8 * 8];
    uint4 p1 = *(const uint4*)&P[(size_t)NN * 1024 + (size_t)r * 1024 + c8 * 8];
    float s[8], t[8];
    unpack8(p0, s); unpack8(p1, t);
#pragma unroll
    for (int q = 0; q < 8; ++q) s[q] += t[q];
    const float dr = d[r];
    const int cx = (c8 < 64 ? c8 : c8 - 64) * 8;
    const float4 xv0 = *(const float4*)&x[(size_t)r * F0 + cx];
    const float4 xv1 = *(const float4*)&x[(size_t)r * F0 + cx + 4];
    float xv[8] = {xv0.x, xv0.y, xv0.z, xv0.w, xv1.x, xv1.y, xv1.z, xv1.w};
    if (c8 < 64) {
      ushort4 o0, o1;
#pragma unroll
      for (int q = 0; q < 4; ++q) ((ushort*)&o0)[q] = f2bf(dr * s[q] + dr * dr * xv[q]);
#pragma unroll
      for (int q = 0; q < 4; ++q) ((ushort*)&o1)[q] = f2bf(dr * s[q + 4] + dr * dr * xv[q + 4]);
      *(ushort4*)&U1b[(size_t)r * F0 + cx] = o0;
      *(ushort4*)&U1b[(size_t)r * F0 + cx + 4] = o1;
    } else {
      const float ri = rinv[r];
#pragma unroll
      for (int q = 0; q < 8; ++q) {
        float Y = ri * xv[q];
        float u2 = dr * s[q] + dr * dr * ri * xv[q];
        ls -= Y * u2;
      }
    }
  }
  red[threadIdx.x] = ls;
  __syncthreads();
  for (int off = 128; off > 0; off >>= 1) {
    if (threadIdx.x < off) red[threadIdx.x] += red[threadIdx.x + off];
    __syncthreads();
  }
  if (threadIdx.x == 0) atomicAdd(loss, red[0]);
}

// ---------- mode-1 GEMM with epilogue: H0b = bf16(relu), H0bT = bf16(d*relu)^T ----------
__global__ __launch_bounds__(256) void k_gemm1(const ushort* __restrict__ A,
                                               const ushort* __restrict__ B,
                                               const float* __restrict__ d,
                                               ushort* __restrict__ H0b,
                                               ushort* __restrict__ H0bT) {
  __shared__ ushort As[128 * 32];
  __shared__ ushort Bs[128 * 32];
  const int i0 = blockIdx.x * 128, j0 = blockIdx.y * 128;
  const int t = threadIdx.x;
  const int lane = t & 63, w = t >> 6;
  const int wr = w >> 1, wc = w & 1;
  f32x4 acc[4][4] = {};
  const int e0 = t, e1 = t + 256;
  const ushort* ag0 = A + (size_t)(i0 + (e0 >> 2)) * F0 + (e0 & 3) * 8;
  const ushort* ag1 = A + (size_t)(i0 + (e1 >> 2)) * F0 + (e1 & 3) * 8;
  const ushort* bg0 = B + (size_t)(j0 + (e0 >> 2)) * F0 + (e0 & 3) * 8;
  const ushort* bg1 = B + (size_t)(j0 + (e1 >> 2)) * F0 + (e1 & 3) * 8;
  ushort* la0 = &As[w * 512];
  ushort* la1 = &As[2048 + w * 512];
  ushort* lb0 = &Bs[w * 512];
  ushort* lb1 = &Bs[2048 + w * 512];
  const int abase = (wr * 64 + (lane & 15)) * 32 + (lane >> 4) * 8;
  const int bbase = (wc * 64 + (lane & 15)) * 32 + (lane >> 4) * 8;
  for (int k0 = 0; k0 < F0; k0 += 32) {
    gload_lds16(ag0 + k0, la0);
    gload_lds16(ag1 + k0, la1);
    gload_lds16(bg0 + k0, lb0);
    gload_lds16(bg1 + k0, lb1);
    __syncthreads();
    bf16x8 af[4], bfr[4];
#pragma unroll
    for (int m = 0; m < 4; ++m) af[m] = *(const bf16x8*)&As[abase + m * 512];
#pragma unroll
    for (int n = 0; n < 4; ++n) bfr[n] = *(const bf16x8*)&Bs[bbase + n * 512];
#pragma unroll
    for (int m = 0; m < 4; ++m)
#pragma unroll
      for (int n = 0; n < 4; ++n)
        acc[m][n] = __builtin_amdgcn_mfma_f32_16x16x32_bf16(af[m], bfr[n], acc[m][n], 0, 0, 0);
    __syncthreads();
  }
#pragma unroll
  for (int m = 0; m < 4; ++m) {
    const int rb = i0 + wr * 64 + m * 16 + (lane >> 4) * 4;
#pragma unroll
    for (int n = 0; n < 4; ++n) {
      const int j = j0 + wc * 64 + n * 16 + (lane & 15);
      f32x4 v = acc[m][n];
      ushort4 o;
#pragma unroll
      for (int q = 0; q < 4; ++q) {
        float hv = v[q] > 0.f ? v[q] : 0.f;
        H0b[(size_t)(rb + q) * F1 + j] = f2bf(hv);
        ((ushort*)&o)[q] = f2bf(d[rb + q] * hv);
      }
      *(ushort4*)&H0bT[(size_t)j * NN + rb] = o;
    }
  }
}

// ---------- k_out: combine mode-2 partials into Uh (LDS) then @ W1 ----------
__global__ __launch_bounds__(256) void k_out(const ushort* __restrict__ PH,
                                             const ushort* __restrict__ H0b,
                                             const float* __restrict__ d,
                                             const float* __restrict__ W1,
                                             float* __restrict__ outp) {
  __shared__ float W1s[F1 * F2];
  __shared__ float Uh[16][F1];
  for (int idx = threadIdx.x; idx < F1 * F2; idx += 256) W1s[idx] = W1[idx];
  const int r = threadIdx.x >> 4;
  const int i = blockIdx.x * 16 + r;
  const int c0 = (threadIdx.x & 15) * 16;
  const float di = d[i];
#pragma unroll
  for (int cc = 0; cc < 16; cc += 8) {
    const int c = c0 + cc;
    float s[8] = {};
#pragma unroll
    for (int ks = 0; ks < 8; ++ks) {
      uint4 pv = *(const uint4*)&PH[(size_t)ks * NN * F1 + (size_t)i * F1 + c];
      float t[8]; unpack8(pv, t);
#pragma unroll
      for (int q = 0; q < 8; ++q) s[q] += t[q];
    }
    uint4 hv = *(const uint4*)&H0b[(size_t)i * F1 + c];
    float h[8]; unpack8(hv, h);
#pragma unroll
    for (int q = 0; q < 8; ++q) Uh[r][c + q] = di * s[q] + di * di * h[q];
  }
  __syncthreads();
  const int f = threadIdx.x & 15;
  float acc = 0.f;
#pragma unroll 8
  for (int k = 0; k < F1; ++k) acc += Uh[r][k] * W1s[k * F2 + f];
  outp[(size_t)i * F2 + f] = acc;
}

extern "C" void kernel_launch(void* const* d_in, const int* in_sizes, int n_in,
                              void* d_out, int out_size, void* d_ws, size_t ws_size,
                              hipStream_t stream) {
  const float* x = (const float*)d_in[0];
  const float* adj = (const float*)d_in[1];
  const float* W0 = (const float*)d_in[4];
  const float* W1 = (const float*)d_in[5];
  float* out = (float*)d_out;
  float* loss = out + (size_t)NN * F2;

  float* ws = (float*)d_ws;
  // small vectors
  float* d_v = ws;            // 8192
  float* rs_n = ws + 8192;    // 8192
  float* cs = ws + 16384;     // 8192
  float* rinv = ws + 24576;   // 8192
  float* wbuf = ws + 32768;   // 8192
  // adjb: bf16 [8192][8192]
  ushort* adjb = (ushort*)(ws + 65536);
  // regionB (4,194,304 floats): BxT first; later U1b | H0b | H0bT
  float* RB = ws + 65536 + (size_t)NN * NN / 2;
  ushort* BxT = (ushort*)RB;                         // [1024][8192] bf16
  ushort* U1b = (ushort*)RB;                         // [8192][512]  bf16 (after BxT dead)
  ushort* H0b = (ushort*)(RB + 2097152);             // [8192][256]  bf16
  ushort* H0bT = (ushort*)(RB + 3145728);            // [256][8192]  bf16
  // W0T
  ushort* W0T = (ushort*)(RB + 4194304);             // [256][512] bf16 (32768 floats)
  // regionC (8,388,608 floats): mode0 partials P[2][8192][1024] bf16;
  // later mode2 partials PH[8][8192][256] bf16
  ushort* P = (ushort*)(RB + 4194304 + 32768);
  ushort* PH = P;

  hipMemsetAsync(cs, 0, NN * sizeof(float), stream);
  hipMemsetAsync(loss, 0, sizeof(float), stream);

  k_pass1<<<NN, 256, 0, stream>>>(adj, adjb, d_v);
  k_wrowsum<<<NN, 256, 0, stream>>>(adjb, d_v, rs_n);
  k_colsum<<<dim3(NN / 2048, NN / 128), 256, 0, stream>>>(adjb, d_v, cs);
  k_finalize<<<NN / 256, 256, 0, stream>>>(d_v, rs_n, cs, rinv, wbuf);

  k_buildBxT<<<dim3(NN / 64, F0 / 64), 256, 0, stream>>>(x, d_v, rinv, wbuf, BxT, loss);
  k_buildW0T<<<dim3(F0 / 64, F1 / 64), 256, 0, stream>>>(W0, W0T);

  // mode 0: [8192 x 1024] = adjb @ BxT^T, split-K x2
  k_gemm_part<<<dim3(NN / 128, 1024 / 128, 2), 256, 0, stream>>>(
      adjb, NN, BxT, NN, NN / 2, P, 1024);
  k_combine0<<<2048, 256, 0, stream>>>(P, x, d_v, rinv, U1b, loss);

  // mode 1: H0 = relu(U1 @ W0)
  k_gemm1<<<dim3(NN / 128, F1 / 128), 256, 0, stream>>>(U1b, W0T, d_v, H0b, H0bT);

  // mode 2: [8192 x 256] = adjb @ H0bT^T, split-K x8
  k_gemm_part<<<dim3(NN / 128, F1 / 128, 8), 256, 0, stream>>>(
      adjb, NN, H0bT, NN, NN / 8, PH, F1);

  // combine + final GEMM
  k_out<<<NN / 16, 256, 0, stream>>>(PH, H0b, d_v, W1, out);
}

// Round 4
// 396.718 us; speedup vs baseline: 12.2181x; 1.2878x over previous
//
#include <hip/hip_runtime.h>

#define NN 8192
#define F0 512
#define F1 256
#define F2 16

typedef __attribute__((ext_vector_type(8))) short bf16x8;
typedef __attribute__((ext_vector_type(4))) float f32x4;

__device__ __forceinline__ ushort f2bf(float f) {
  unsigned u = __float_as_uint(f);
  u += 0x7FFFu + ((u >> 16) & 1u);  // RNE
  return (ushort)(u >> 16);
}
__device__ __forceinline__ float bf2f(ushort u) {
  return __uint_as_float(((unsigned)u) << 16);
}
__device__ __forceinline__ void unpack8(uint4 a, float* f) {
  f[0] = bf2f((ushort)(a.x & 0xffff)); f[1] = bf2f((ushort)(a.x >> 16));
  f[2] = bf2f((ushort)(a.y & 0xffff)); f[3] = bf2f((ushort)(a.y >> 16));
  f[4] = bf2f((ushort)(a.z & 0xffff)); f[5] = bf2f((ushort)(a.z >> 16));
  f[6] = bf2f((ushort)(a.w & 0xffff)); f[7] = bf2f((ushort)(a.w >> 16));
}
__device__ __forceinline__ void gload_lds16(const ushort* g, ushort* l) {
  __builtin_amdgcn_global_load_lds((const __attribute__((address_space(1))) void*)g,
                                   (__attribute__((address_space(3))) void*)l, 16, 0, 0);
}

// ---------- pass1: rowsum (fp32 exact) + adj -> bf16 ----------
__global__ __launch_bounds__(256) void k_pass1(const float* __restrict__ adj,
                                               ushort* __restrict__ adjb,
                                               float* __restrict__ d) {
  __shared__ float red[256];
  const size_t base = (size_t)blockIdx.x * NN;
  float s = 0.f;
  for (int j = threadIdx.x * 4; j < NN; j += 1024) {
    float4 v = *(const float4*)&adj[base + j];
    s += (v.x + v.y) + (v.z + v.w);
    ushort4 o;
    o.x = f2bf(v.x); o.y = f2bf(v.y); o.z = f2bf(v.z); o.w = f2bf(v.w);
    *(ushort4*)&adjb[base + j] = o;
  }
  red[threadIdx.x] = s;
  __syncthreads();
  for (int off = 128; off > 0; off >>= 1) {
    if (threadIdx.x < off) red[threadIdx.x] += red[threadIdx.x + off];
    __syncthreads();
  }
  if (threadIdx.x == 0) d[blockIdx.x] = rsqrtf(1.0f + red[0]);
}

// ---------- rs_n[i] = d_i * sum_j adjb[i][j] d_j + d_i^2 ----------
__global__ __launch_bounds__(256) void k_wrowsum(const ushort* __restrict__ adjb,
                                                 const float* __restrict__ d,
                                                 float* __restrict__ rs_n) {
  __shared__ float red[256];
  float s = 0.f;
  for (int p = threadIdx.x; p < NN / 8; p += 256) {
    uint4 pk = *(const uint4*)&adjb[(size_t)blockIdx.x * NN + p * 8];
    float t[8]; unpack8(pk, t);
    const float4 d0 = *(const float4*)&d[p * 8];
    const float4 d1 = *(const float4*)&d[p * 8 + 4];
    s += t[0] * d0.x + t[1] * d0.y + t[2] * d0.z + t[3] * d0.w
       + t[4] * d1.x + t[5] * d1.y + t[6] * d1.z + t[7] * d1.w;
  }
  red[threadIdx.x] = s;
  __syncthreads();
  for (int off = 128; off > 0; off >>= 1) {
    if (threadIdx.x < off) red[threadIdx.x] += red[threadIdx.x + off];
    __syncthreads();
  }
  if (threadIdx.x == 0) {
    float di = d[blockIdx.x];
    rs_n[blockIdx.x] = di * red[0] + di * di;
  }
}

// ---------- cs_raw[c] += sum_i adjb[i][c] d_i ----------
__global__ __launch_bounds__(256) void k_colsum(const ushort* __restrict__ adjb,
                                                const float* __restrict__ d,
                                                float* __restrict__ cs) {
  const int c0 = blockIdx.x * 2048 + threadIdx.x * 8;
  const int r0 = blockIdx.y * 128;
  float acc[8] = {};
  for (int i = 0; i < 128; ++i) {
    uint4 v = *(const uint4*)&adjb[(size_t)(r0 + i) * NN + c0];
    float t[8]; unpack8(v, t);
    float di = d[r0 + i];
#pragma unroll
    for (int q = 0; q < 8; ++q) acc[q] += t[q] * di;
  }
#pragma unroll
  for (int q = 0; q < 8; ++q) atomicAdd(&cs[c0 + q], acc[q]);
}

__global__ __launch_bounds__(256) void k_finalize(const float* __restrict__ d,
                                                  const float* __restrict__ rs_n,
                                                  const float* __restrict__ cs_raw,
                                                  float* __restrict__ rinv,
                                                  float* __restrict__ wbuf) {
  int i = blockIdx.x * 256 + threadIdx.x;
  float di = d[i];
  float cs_n = di * cs_raw[i] + di * di;
  float rs = 0.5f * (rs_n[i] + cs_n);
  rinv[i] = rsqrtf(rs + 0.001f);
  wbuf[i] = rs / (rs + 0.001f);  // rssym * rinv^2
}

// ---------- BxT build + loss term A = sum_i w_i * |x_i|^2 ----------
__global__ __launch_bounds__(256) void k_buildBxT(const float* __restrict__ x,
                                                  const float* __restrict__ d,
                                                  const float* __restrict__ rinv,
                                                  const float* __restrict__ wbuf,
                                                  ushort* __restrict__ BxT,
                                                  float* __restrict__ loss) {
  __shared__ float tile[64][65];
  __shared__ float red[256];
  const int k0 = blockIdx.x * 64, j0 = blockIdx.y * 64;
  const int tc = threadIdx.x & 15, tr = threadIdx.x >> 4;
  float s = 0.f;
#pragma unroll
  for (int it = 0; it < 4; ++it) {
    int r = tr + it * 16;
    float4 v = *(const float4*)&x[(size_t)(k0 + r) * F0 + j0 + tc * 4];
    s += wbuf[k0 + r] * (v.x * v.x + v.y * v.y + v.z * v.z + v.w * v.w);
    tile[r][tc * 4 + 0] = v.x; tile[r][tc * 4 + 1] = v.y;
    tile[r][tc * 4 + 2] = v.z; tile[r][tc * 4 + 3] = v.w;
  }
  red[threadIdx.x] = s;
  __syncthreads();
#pragma unroll
  for (int it = 0; it < 4; ++it) {
    int j = tr + it * 16;
    int kk = tc * 4;
    ushort4 o0, o1;
#pragma unroll
    for (int q = 0; q < 4; ++q) {
      int k = k0 + kk + q;
      float val = tile[kk + q][j];
      ((ushort*)&o0)[q] = f2bf(d[k] * val);
      ((ushort*)&o1)[q] = f2bf(d[k] * rinv[k] * val);
    }
    *(ushort4*)&BxT[(size_t)(j0 + j) * NN + k0 + kk] = o0;
    *(ushort4*)&BxT[(size_t)(F0 + j0 + j) * NN + k0 + kk] = o1;
  }
  __syncthreads();
  for (int off = 128; off > 0; off >>= 1) {
    if (threadIdx.x < off) red[threadIdx.x] += red[threadIdx.x + off];
    __syncthreads();
  }
  if (threadIdx.x == 0) atomicAdd(loss, red[0]);
}

// ---------- W0T[j][k] = bf16(W0[k][j]) ----------
__global__ __launch_bounds__(256) void k_buildW0T(const float* __restrict__ W0,
                                                  ushort* __restrict__ W0T) {
  __shared__ float tile[64][65];
  const int k0 = blockIdx.x * 64, j0 = blockIdx.y * 64;
  const int tc = threadIdx.x & 15, tr = threadIdx.x >> 4;
#pragma unroll
  for (int it = 0; it < 4; ++it) {
    int r = tr + it * 16;
    float4 v = *(const float4*)&W0[(size_t)(k0 + r) * F1 + j0 + tc * 4];
    tile[r][tc * 4 + 0] = v.x; tile[r][tc * 4 + 1] = v.y;
    tile[r][tc * 4 + 2] = v.z; tile[r][tc * 4 + 3] = v.w;
  }
  __syncthreads();
#pragma unroll
  for (int it = 0; it < 4; ++it) {
    int j = tr + it * 16;
    int kk = tc * 4;
    ushort4 o;
#pragma unroll
    for (int q = 0; q < 4; ++q) ((ushort*)&o)[q] = f2bf(tile[kk + q][j]);
    *(ushort4*)&W0T[(size_t)(j0 + j) * F0 + k0 + kk] = o;
  }
}

// ============ 256x256-tile 8-phase MFMA GEMM (T2+T3+T4+T5) ============
// C[8192 x N] = A[8192 x K] @ B[N x K]^T, K = NT*64 per z-slice, bf16 partials out.
// 512 thr = 8 waves (2M x 4N); per-wave C = 128x64 (8x4 frags); BK=64 (2 k-steps).
// LDS 128KB: buf{0,1} x region{A0,A1,B0,B1} x 16KB half-tiles [128 rows][64 cols].
// Swizzle: phys_byte = logical ^ ((row&7)<<4)  (involution; staged via pre-swizzled
// global source + linear gload_lds dest; ds_reads apply same XOR).
template <int NT>
__global__ __launch_bounds__(512, 2) void k_gemm8(
    const ushort* __restrict__ A, const ushort* __restrict__ B,
    ushort* __restrict__ P, int ldn) {
  __shared__ ushort lds[65536];  // 128 KiB
  const int t = threadIdx.x, lane = t & 63, w = t >> 6;
  const int wr = w >> 2, wc = w & 3;
  const int i0 = blockIdx.x * 256, j0 = blockIdx.y * 256;
  const size_t kbase = (size_t)blockIdx.z * (NT * 64);

  // staging source precompute (inverse-swizzled global address, rule #21)
  int srow[2], scol[2];
#pragma unroll
  for (int q = 0; q < 2; ++q) {
    int Pl = q * 8192 + t * 16;                  // physical byte in half-tile
    int L = Pl ^ (((Pl >> 7) & 7) << 4);         // logical byte
    srow[q] = L >> 7;
    scol[q] = (L & 127) >> 1;                    // elements
  }
  const ushort* src[4][2];
#pragma unroll
  for (int q = 0; q < 2; ++q) {
    src[0][q] = A + (size_t)(i0 + srow[q]) * NN + kbase + scol[q];        // A0
    src[1][q] = A + (size_t)(i0 + 128 + srow[q]) * NN + kbase + scol[q];  // A1
    src[2][q] = B + (size_t)(j0 + srow[q]) * NN + kbase + scol[q];        // B0
    src[3][q] = B + (size_t)(j0 + 128 + srow[q]) * NN + kbase + scol[q];  // B1
  }

  auto STAGE = [&](int reg, int tt, int bb) {
    ushort* dstb = &lds[bb * 32768 + reg * 8192 + w * 512];
    gload_lds16(src[reg][0] + tt * 64, dstb);
    gload_lds16(src[reg][1] + tt * 64, dstb + 4096);
  };

  // swizzled read offsets (ushort units)
  const int k0off = ((((lane >> 4) * 16) ^ ((lane & 7) << 4)) >> 1);
  const int k1off = (((64 + (lane >> 4) * 16) ^ ((lane & 7) << 4)) >> 1);
  auto LDA = [&](int bb, int mf, int kk) -> bf16x8 {
    return *(const bf16x8*)&lds[bb * 32768 + wr * 8192 +
                                (mf * 16 + (lane & 15)) * 64 + (kk ? k1off : k0off)];
  };
  auto LDB = [&](int bb, int nf, int kk) -> bf16x8 {
    return *(const bf16x8*)&lds[bb * 32768 + (2 + (wc >> 1)) * 8192 +
                                ((wc & 1) * 64 + nf * 16 + (lane & 15)) * 64 +
                                (kk ? k1off : k0off)];
  };
  auto MM = [&](bf16x8 av, bf16x8 bv, f32x4 c) -> f32x4 {
    return __builtin_amdgcn_mfma_f32_16x16x32_bf16(av, bv, c, 0, 0, 0);
  };

  f32x4 acc[8][4] = {};
  bf16x8 a[4][2], b01[2][2], b23[2][2];

  // prologue: t0 fully -> buf0 (oldest 8 loads), t1 B0,B1 -> buf1
  STAGE(2, 0, 0); STAGE(3, 0, 0); STAGE(0, 0, 0); STAGE(1, 0, 0);
  STAGE(2, 1, 1); STAGE(3, 1, 1);
  asm volatile("s_waitcnt vmcnt(4)" ::: "memory");
  __builtin_amdgcn_sched_barrier(0);
  __builtin_amdgcn_s_barrier();

  constexpr int NIT = NT / 2;
#pragma unroll 1
  for (int i = 0; i < NIT; ++i) {
    const bool nl = (i + 1 < NIT);
    const int tb = 2 * i + 1, t2 = 2 * i + 2, t3 = 2 * i + 3;

    // ---------- phases 1-4: compute tile 2i from buf0 ----------
    // ph1: read A m0-3 + B n0-1; stage A0(tb)->buf1
#pragma unroll
    for (int m = 0; m < 4; ++m) { a[m][0] = LDA(0, m, 0); a[m][1] = LDA(0, m, 1); }
#pragma unroll
    for (int n = 0; n < 2; ++n) { b01[n][0] = LDB(0, n, 0); b01[n][1] = LDB(0, n, 1); }
    STAGE(0, tb, 1);
    __builtin_amdgcn_s_barrier();
    asm volatile("s_waitcnt lgkmcnt(0)" ::: "memory");
    __builtin_amdgcn_sched_barrier(0);
    __builtin_amdgcn_s_setprio(1);
#pragma unroll
    for (int m = 0; m < 4; ++m)
#pragma unroll
      for (int n = 0; n < 2; ++n) {
        acc[m][n] = MM(a[m][0], b01[n][0], acc[m][n]);
        acc[m][n] = MM(a[m][1], b01[n][1], acc[m][n]);
      }
    __builtin_amdgcn_s_setprio(0);
    __builtin_amdgcn_sched_barrier(0);
    __builtin_amdgcn_s_barrier();

    // ph2: read B n2-3; stage A1(tb)->buf1
#pragma unroll
    for (int n = 0; n < 2; ++n) { b23[n][0] = LDB(0, 2 + n, 0); b23[n][1] = LDB(0, 2 + n, 1); }
    STAGE(1, tb, 1);
    __builtin_amdgcn_s_barrier();
    asm volatile("s_waitcnt lgkmcnt(0)" ::: "memory");
    __builtin_amdgcn_sched_barrier(0);
    __builtin_amdgcn_s_setprio(1);
#pragma unroll
    for (int m = 0; m < 4; ++m)
#pragma unroll
      for (int n = 0; n < 2; ++n) {
        acc[m][2 + n] = MM(a[m][0], b23[n][0], acc[m][2 + n]);
        acc[m][2 + n] = MM(a[m][1], b23[n][1], acc[m][2 + n]);
      }
    __builtin_amdgcn_s_setprio(0);
    __builtin_amdgcn_sched_barrier(0);
    __builtin_amdgcn_s_barrier();

    // ph3: read A m4-7; stage B0(t2)->buf0 (B0 last read ph2)
#pragma unroll
    for (int m = 0; m < 4; ++m) { a[m][0] = LDA(0, 4 + m, 0); a[m][1] = LDA(0, 4 + m, 1); }
    if (nl) STAGE(2, t2, 0);
    __builtin_amdgcn_s_barrier();
    asm volatile("s_waitcnt lgkmcnt(0)" ::: "memory");
    __builtin_amdgcn_sched_barrier(0);
    __builtin_amdgcn_s_setprio(1);
#pragma unroll
    for (int m = 0; m < 4; ++m)
#pragma unroll
      for (int n = 0; n < 2; ++n) {
        acc[4 + m][2 + n] = MM(a[m][0], b23[n][0], acc[4 + m][2 + n]);
        acc[4 + m][2 + n] = MM(a[m][1], b23[n][1], acc[4 + m][2 + n]);
      }
    __builtin_amdgcn_s_setprio(0);
    __builtin_amdgcn_sched_barrier(0);
    __builtin_amdgcn_s_barrier();

    // ph4: no reads; stage B1(t2)->buf0; vmcnt checkpoint for tile tb
    if (nl) STAGE(3, t2, 0);
    __builtin_amdgcn_s_barrier();
    __builtin_amdgcn_s_setprio(1);
#pragma unroll
    for (int m = 0; m < 4; ++m)
#pragma unroll
      for (int n = 0; n < 2; ++n) {
        acc[4 + m][n] = MM(a[m][0], b01[n][0], acc[4 + m][n]);
        acc[4 + m][n] = MM(a[m][1], b01[n][1], acc[4 + m][n]);
      }
    __builtin_amdgcn_s_setprio(0);
    if (nl) { asm volatile("s_waitcnt vmcnt(4)" ::: "memory"); }
    else    { asm volatile("s_waitcnt vmcnt(0)" ::: "memory"); }
    __builtin_amdgcn_sched_barrier(0);
    __builtin_amdgcn_s_barrier();

    // ---------- phases 5-8: compute tile 2i+1 from buf1 ----------
    // ph5: read A m0-3 + B n0-1; stage A0(t2)->buf0
#pragma unroll
    for (int m = 0; m < 4; ++m) { a[m][0] = LDA(1, m, 0); a[m][1] = LDA(1, m, 1); }
#pragma unroll
    for (int n = 0; n < 2; ++n) { b01[n][0] = LDB(1, n, 0); b01[n][1] = LDB(1, n, 1); }
    if (nl) STAGE(0, t2, 0);
    __builtin_amdgcn_s_barrier();
    asm volatile("s_waitcnt lgkmcnt(0)" ::: "memory");
    __builtin_amdgcn_sched_barrier(0);
    __builtin_amdgcn_s_setprio(1);
#pragma unroll
    for (int m = 0; m < 4; ++m)
#pragma unroll
      for (int n = 0; n < 2; ++n) {
        acc[m][n] = MM(a[m][0], b01[n][0], acc[m][n]);
        acc[m][n] = MM(a[m][1], b01[n][1], acc[m][n]);
      }
    __builtin_amdgcn_s_setprio(0);
    __builtin_amdgcn_sched_barrier(0);
    __builtin_amdgcn_s_barrier();

    // ph6: read B n2-3; stage A1(t2)->buf0
#pragma unroll
    for (int n = 0; n < 2; ++n) { b23[n][0] = LDB(1, 2 + n, 0); b23[n][1] = LDB(1, 2 + n, 1); }
    if (nl) STAGE(1, t2, 0);
    __builtin_amdgcn_s_barrier();
    asm volatile("s_waitcnt lgkmcnt(0)" ::: "memory");
    __builtin_amdgcn_sched_barrier(0);
    __builtin_amdgcn_s_setprio(1);
#pragma unroll
    for (int m = 0; m < 4; ++m)
#pragma unroll
      for (int n = 0; n < 2; ++n) {
        acc[m][2 + n] = MM(a[m][0], b23[n][0], acc[m][2 + n]);
        acc[m][2 + n] = MM(a[m][1], b23[n][1], acc[m][2 + n]);
      }
    __builtin_amdgcn_s_setprio(0);
    __builtin_amdgcn_sched_barrier(0);
    __builtin_amdgcn_s_barrier();

    // ph7: read A m4-7; stage B0(t3)->buf1 (B0 last read ph6)
#pragma unroll
    for (int m = 0; m < 4; ++m) { a[m][0] = LDA(1, 4 + m, 0); a[m][1] = LDA(1, 4 + m, 1); }
    if (nl) STAGE(2, t3, 1);
    __builtin_amdgcn_s_barrier();
    asm volatile("s_waitcnt lgkmcnt(0)" ::: "memory");
    __builtin_amdgcn_sched_barrier(0);
    __builtin_amdgcn_s_setprio(1);
#pragma unroll
    for (int m = 0; m < 4; ++m)
#pragma unroll
      for (int n = 0; n < 2; ++n) {
        acc[4 + m][2 + n] = MM(a[m][0], b23[n][0], acc[4 + m][2 + n]);
        acc[4 + m][2 + n] = MM(a[m][1], b23[n][1], acc[4 + m][2 + n]);
      }
    __builtin_amdgcn_s_setprio(0);
    __builtin_amdgcn_sched_barrier(0);
    __builtin_amdgcn_s_barrier();

    // ph8: no reads; stage B1(t3)->buf1; vmcnt checkpoint for tile t2
    if (nl) STAGE(3, t3, 1);
    __builtin_amdgcn_s_barrier();
    __builtin_amdgcn_s_setprio(1);
#pragma unroll
    for (int m = 0; m < 4; ++m)
#pragma unroll
      for (int n = 0; n < 2; ++n) {
        acc[4 + m][n] = MM(a[m][0], b01[n][0], acc[4 + m][n]);
        acc[4 + m][n] = MM(a[m][1], b01[n][1], acc[4 + m][n]);
      }
    __builtin_amdgcn_s_setprio(0);
    if (nl) { asm volatile("s_waitcnt vmcnt(4)" ::: "memory"); }
    else    { asm volatile("s_waitcnt vmcnt(0)" ::: "memory"); }
    __builtin_amdgcn_sched_barrier(0);
    __builtin_amdgcn_s_barrier();
  }

  // ---------- epilogue: bf16 partials ----------
  ushort* Pz = P + (size_t)blockIdx.z * NN * ldn;
#pragma unroll
  for (int mf = 0; mf < 8; ++mf) {
    const int rb = i0 + wr * 128 + mf * 16 + (lane >> 4) * 4;
#pragma unroll
    for (int nf = 0; nf < 4; ++nf) {
      const int j = j0 + wc * 64 + nf * 16 + (lane & 15);
      f32x4 v = acc[mf][nf];
#pragma unroll
      for (int q = 0; q < 4; ++q) Pz[(size_t)(rb + q) * ldn + j] = f2bf(v[q]);
    }
  }
}

// ---------- combine mode-0 partials: U1b epilogue + loss term B ----------
__global__ __launch_bounds__(256) void k_combine0(const ushort* __restrict__ P,
                                                  const float* __restrict__ x,
                                                  const float* __restrict__ d,
                                                  const float* __restrict__ rinv,
                                                  ushort* __restrict__ U1b,
                                                  float* __restrict__ loss) {
  __shared__ float red[256];
  float ls = 0.f;
  const int total = NN * 1024 / 8;
  for (int idx = blockIdx.x * 256 + threadIdx.x; idx < total; idx += gridDim.x * 256) {
    const int r = idx >> 7;
    const int c8 = idx & 127;
    uint4 p0 = *(const uint4*)&P[(size_t)r * 1024 + c8 * 8];
    uint4 p1 = *(const uint4*)&P[(size_t)NN * 1024 + (size_t)r * 1024 + c8 * 8];
    float s[8], t[8];
    unpack8(p0, s); unpack8(p1, t);
#pragma unroll
    for (int q = 0; q < 8; ++q) s[q] += t[q];
    const float dr = d[r];
    const int cx = (c8 < 64 ? c8 : c8 - 64) * 8;
    const float4 xv0 = *(const float4*)&x[(size_t)r * F0 + cx];
    const float4 xv1 = *(const float4*)&x[(size_t)r * F0 + cx + 4];
    float xv[8] = {xv0.x, xv0.y, xv0.z, xv0.w, xv1.x, xv1.y, xv1.z, xv1.w};
    if (c8 < 64) {
      ushort4 o0, o1;
#pragma unroll
      for (int q = 0; q < 4; ++q) ((ushort*)&o0)[q] = f2bf(dr * s[q] + dr * dr * xv[q]);
#pragma unroll
      for (int q = 0; q < 4; ++q) ((ushort*)&o1)[q] = f2bf(dr * s[q + 4] + dr * dr * xv[q + 4]);
      *(ushort4*)&U1b[(size_t)r * F0 + cx] = o0;
      *(ushort4*)&U1b[(size_t)r * F0 + cx + 4] = o1;
    } else {
      const float ri = rinv[r];
#pragma unroll
      for (int q = 0; q < 8; ++q) {
        float Y = ri * xv[q];
        float u2 = dr * s[q] + dr * dr * ri * xv[q];
        ls -= Y * u2;
      }
    }
  }
  red[threadIdx.x] = ls;
  __syncthreads();
  for (int off = 128; off > 0; off >>= 1) {
    if (threadIdx.x < off) red[threadIdx.x] += red[threadIdx.x + off];
    __syncthreads();
  }
  if (threadIdx.x == 0) atomicAdd(loss, red[0]);
}

// ---------- mode-1 GEMM with epilogue: H0b = bf16(relu), H0bT = bf16(d*relu)^T ----------
__global__ __launch_bounds__(256) void k_gemm1(const ushort* __restrict__ A,
                                               const ushort* __restrict__ B,
                                               const float* __restrict__ d,
                                               ushort* __restrict__ H0b,
                                               ushort* __restrict__ H0bT) {
  __shared__ ushort As[128 * 32];
  __shared__ ushort Bs[128 * 32];
  const int i0 = blockIdx.x * 128, j0 = blockIdx.y * 128;
  const int t = threadIdx.x;
  const int lane = t & 63, w = t >> 6;
  const int wr = w >> 1, wc = w & 1;
  f32x4 acc[4][4] = {};
  const int e0 = t, e1 = t + 256;
  const ushort* ag0 = A + (size_t)(i0 + (e0 >> 2)) * F0 + (e0 & 3) * 8;
  const ushort* ag1 = A + (size_t)(i0 + (e1 >> 2)) * F0 + (e1 & 3) * 8;
  const ushort* bg0 = B + (size_t)(j0 + (e0 >> 2)) * F0 + (e0 & 3) * 8;
  const ushort* bg1 = B + (size_t)(j0 + (e1 >> 2)) * F0 + (e1 & 3) * 8;
  ushort* la0 = &As[w * 512];
  ushort* la1 = &As[2048 + w * 512];
  ushort* lb0 = &Bs[w * 512];
  ushort* lb1 = &Bs[2048 + w * 512];
  const int abase = (wr * 64 + (lane & 15)) * 32 + (lane >> 4) * 8;
  const int bbase = (wc * 64 + (lane & 15)) * 32 + (lane >> 4) * 8;
  for (int k0 = 0; k0 < F0; k0 += 32) {
    gload_lds16(ag0 + k0, la0);
    gload_lds16(ag1 + k0, la1);
    gload_lds16(bg0 + k0, lb0);
    gload_lds16(bg1 + k0, lb1);
    __syncthreads();
    bf16x8 af[4], bfr[4];
#pragma unroll
    for (int m = 0; m < 4; ++m) af[m] = *(const bf16x8*)&As[abase + m * 512];
#pragma unroll
    for (int n = 0; n < 4; ++n) bfr[n] = *(const bf16x8*)&Bs[bbase + n * 512];
#pragma unroll
    for (int m = 0; m < 4; ++m)
#pragma unroll
      for (int n = 0; n < 4; ++n)
        acc[m][n] = __builtin_amdgcn_mfma_f32_16x16x32_bf16(af[m], bfr[n], acc[m][n], 0, 0, 0);
    __syncthreads();
  }
#pragma unroll
  for (int m = 0; m < 4; ++m) {
    const int rb = i0 + wr * 64 + m * 16 + (lane >> 4) * 4;
#pragma unroll
    for (int n = 0; n < 4; ++n) {
      const int j = j0 + wc * 64 + n * 16 + (lane & 15);
      f32x4 v = acc[m][n];
      ushort4 o;
#pragma unroll
      for (int q = 0; q < 4; ++q) {
        float hv = v[q] > 0.f ? v[q] : 0.f;
        H0b[(size_t)(rb + q) * F1 + j] = f2bf(hv);
        ((ushort*)&o)[q] = f2bf(d[rb + q] * hv);
      }
      *(ushort4*)&H0bT[(size_t)j * NN + rb] = o;
    }
  }
}

// ---------- k_out: combine mode-2 partials into Uh (LDS) then @ W1 ----------
__global__ __launch_bounds__(256) void k_out(const ushort* __restrict__ PH,
                                             const ushort* __restrict__ H0b,
                                             const float* __restrict__ d,
                                             const float* __restrict__ W1,
                                             float* __restrict__ outp) {
  __shared__ float W1s[F1 * F2];
  __shared__ float Uh[16][F1];
  for (int idx = threadIdx.x; idx < F1 * F2; idx += 256) W1s[idx] = W1[idx];
  const int r = threadIdx.x >> 4;
  const int i = blockIdx.x * 16 + r;
  const int c0 = (threadIdx.x & 15) * 16;
  const float di = d[i];
#pragma unroll
  for (int cc = 0; cc < 16; cc += 8) {
    const int c = c0 + cc;
    float s[8] = {};
#pragma unroll
    for (int ks = 0; ks < 8; ++ks) {
      uint4 pv = *(const uint4*)&PH[(size_t)ks * NN * F1 + (size_t)i * F1 + c];
      float t[8]; unpack8(pv, t);
#pragma unroll
      for (int q = 0; q < 8; ++q) s[q] += t[q];
    }
    uint4 hv = *(const uint4*)&H0b[(size_t)i * F1 + c];
    float h[8]; unpack8(hv, h);
#pragma unroll
    for (int q = 0; q < 8; ++q) Uh[r][c + q] = di * s[q] + di * di * h[q];
  }
  __syncthreads();
  const int f = threadIdx.x & 15;
  float acc = 0.f;
#pragma unroll 8
  for (int k = 0; k < F1; ++k) acc += Uh[r][k] * W1s[k * F2 + f];
  outp[(size_t)i * F2 + f] = acc;
}

extern "C" void kernel_launch(void* const* d_in, const int* in_sizes, int n_in,
                              void* d_out, int out_size, void* d_ws, size_t ws_size,
                              hipStream_t stream) {
  const float* x = (const float*)d_in[0];
  const float* adj = (const float*)d_in[1];
  const float* W0 = (const float*)d_in[4];
  const float* W1 = (const float*)d_in[5];
  float* out = (float*)d_out;
  float* loss = out + (size_t)NN * F2;

  float* ws = (float*)d_ws;
  float* d_v = ws;            // 8192
  float* rs_n = ws + 8192;    // 8192
  float* cs = ws + 16384;     // 8192
  float* rinv = ws + 24576;   // 8192
  float* wbuf = ws + 32768;   // 8192
  ushort* adjb = (ushort*)(ws + 65536);              // [8192][8192] bf16
  float* RB = ws + 65536 + (size_t)NN * NN / 2;
  ushort* BxT = (ushort*)RB;                         // [1024][8192] bf16
  ushort* U1b = (ushort*)RB;                         // [8192][512]  bf16 (after BxT dead)
  ushort* H0b = (ushort*)(RB + 2097152);             // [8192][256]  bf16
  ushort* H0bT = (ushort*)(RB + 3145728);            // [256][8192]  bf16
  ushort* W0T = (ushort*)(RB + 4194304);             // [256][512] bf16
  ushort* P = (ushort*)(RB + 4194304 + 32768);       // mode0: [2][8192][1024] bf16
  ushort* PH = P;                                    // mode2: [8][8192][256]  bf16

  hipMemsetAsync(cs, 0, NN * sizeof(float), stream);
  hipMemsetAsync(loss, 0, sizeof(float), stream);

  k_pass1<<<NN, 256, 0, stream>>>(adj, adjb, d_v);
  k_wrowsum<<<NN, 256, 0, stream>>>(adjb, d_v, rs_n);
  k_colsum<<<dim3(NN / 2048, NN / 128), 256, 0, stream>>>(adjb, d_v, cs);
  k_finalize<<<NN / 256, 256, 0, stream>>>(d_v, rs_n, cs, rinv, wbuf);

  k_buildBxT<<<dim3(NN / 64, F0 / 64), 256, 0, stream>>>(x, d_v, rinv, wbuf, BxT, loss);
  k_buildW0T<<<dim3(F0 / 64, F1 / 64), 256, 0, stream>>>(W0, W0T);

  // mode 0: [8192 x 1024] = adjb @ BxT^T, 256^2 8-phase, split-K x2 (K=4096 each)
  k_gemm8<64><<<dim3(NN / 256, 1024 / 256, 2), 512, 0, stream>>>(adjb, BxT, P, 1024);
  k_combine0<<<2048, 256, 0, stream>>>(P, x, d_v, rinv, U1b, loss);

  // mode 1: H0 = relu(U1 @ W0)
  k_gemm1<<<dim3(NN / 128, F1 / 128), 256, 0, stream>>>(U1b, W0T, d_v, H0b, H0bT);

  // mode 2: [8192 x 256] = adjb @ H0bT^T, 256^2 8-phase, split-K x8 (K=1024 each)
  k_gemm8<16><<<dim3(NN / 256, F1 / 256, 8), 512, 0, stream>>>(adjb, H0bT, PH, F1);

  // combine + final GEMM
  k_out<<<NN / 16, 256, 0, stream>>>(PH, H0b, d_v, W1, out);
}

// Round 5
// 394.420 us; speedup vs baseline: 12.2893x; 1.0058x over previous
//
#include <hip/hip_runtime.h>

#define NN 8192
#define F0 512
#define F1 256
#define F2 16

typedef __attribute__((ext_vector_type(8))) short bf16x8;
typedef __attribute__((ext_vector_type(4))) float f32x4;

__device__ __forceinline__ ushort f2bf(float f) {
  unsigned u = __float_as_uint(f);
  u += 0x7FFFu + ((u >> 16) & 1u);  // RNE
  return (ushort)(u >> 16);
}
__device__ __forceinline__ float bf2f(ushort u) {
  return __uint_as_float(((unsigned)u) << 16);
}
__device__ __forceinline__ void unpack8(uint4 a, float* f) {
  f[0] = bf2f((ushort)(a.x & 0xffff)); f[1] = bf2f((ushort)(a.x >> 16));
  f[2] = bf2f((ushort)(a.y & 0xffff)); f[3] = bf2f((ushort)(a.y >> 16));
  f[4] = bf2f((ushort)(a.z & 0xffff)); f[5] = bf2f((ushort)(a.z >> 16));
  f[6] = bf2f((ushort)(a.w & 0xffff)); f[7] = bf2f((ushort)(a.w >> 16));
}
__device__ __forceinline__ void gload_lds16(const ushort* g, ushort* l) {
  __builtin_amdgcn_global_load_lds((const __attribute__((address_space(1))) void*)g,
                                   (__attribute__((address_space(3))) void*)l, 16, 0, 0);
}

// ---------- pass1: rowsum (fp32 exact) + adj -> bf16 ----------
__global__ __launch_bounds__(256) void k_pass1(const float* __restrict__ adj,
                                               ushort* __restrict__ adjb,
                                               float* __restrict__ d) {
  __shared__ float red[256];
  const size_t base = (size_t)blockIdx.x * NN;
  float s = 0.f;
  for (int j = threadIdx.x * 4; j < NN; j += 1024) {
    float4 v = *(const float4*)&adj[base + j];
    s += (v.x + v.y) + (v.z + v.w);
    ushort4 o;
    o.x = f2bf(v.x); o.y = f2bf(v.y); o.z = f2bf(v.z); o.w = f2bf(v.w);
    *(ushort4*)&adjb[base + j] = o;
  }
  red[threadIdx.x] = s;
  __syncthreads();
  for (int off = 128; off > 0; off >>= 1) {
    if (threadIdx.x < off) red[threadIdx.x] += red[threadIdx.x + off];
    __syncthreads();
  }
  if (threadIdx.x == 0) d[blockIdx.x] = rsqrtf(1.0f + red[0]);
}

// ---------- rs_n[i] = d_i * sum_j adjb[i][j] d_j + d_i^2 ----------
__global__ __launch_bounds__(256) void k_wrowsum(const ushort* __restrict__ adjb,
                                                 const float* __restrict__ d,
                                                 float* __restrict__ rs_n) {
  __shared__ float red[256];
  float s = 0.f;
  for (int p = threadIdx.x; p < NN / 8; p += 256) {
    uint4 pk = *(const uint4*)&adjb[(size_t)blockIdx.x * NN + p * 8];
    float t[8]; unpack8(pk, t);
    const float4 d0 = *(const float4*)&d[p * 8];
    const float4 d1 = *(const float4*)&d[p * 8 + 4];
    s += t[0] * d0.x + t[1] * d0.y + t[2] * d0.z + t[3] * d0.w
       + t[4] * d1.x + t[5] * d1.y + t[6] * d1.z + t[7] * d1.w;
  }
  red[threadIdx.x] = s;
  __syncthreads();
  for (int off = 128; off > 0; off >>= 1) {
    if (threadIdx.x < off) red[threadIdx.x] += red[threadIdx.x + off];
    __syncthreads();
  }
  if (threadIdx.x == 0) {
    float di = d[blockIdx.x];
    rs_n[blockIdx.x] = di * red[0] + di * di;
  }
}

// ---------- cs_raw[c] += sum_i adjb[i][c] d_i ----------
__global__ __launch_bounds__(256) void k_colsum(const ushort* __restrict__ adjb,
                                                const float* __restrict__ d,
                                                float* __restrict__ cs) {
  const int c0 = blockIdx.x * 2048 + threadIdx.x * 8;
  const int r0 = blockIdx.y * 128;
  float acc[8] = {};
  for (int i = 0; i < 128; ++i) {
    uint4 v = *(const uint4*)&adjb[(size_t)(r0 + i) * NN + c0];
    float t[8]; unpack8(v, t);
    float di = d[r0 + i];
#pragma unroll
    for (int q = 0; q < 8; ++q) acc[q] += t[q] * di;
  }
#pragma unroll
  for (int q = 0; q < 8; ++q) atomicAdd(&cs[c0 + q], acc[q]);
}

__global__ __launch_bounds__(256) void k_finalize(const float* __restrict__ d,
                                                  const float* __restrict__ rs_n,
                                                  const float* __restrict__ cs_raw,
                                                  float* __restrict__ rinv,
                                                  float* __restrict__ wbuf) {
  int i = blockIdx.x * 256 + threadIdx.x;
  float di = d[i];
  float cs_n = di * cs_raw[i] + di * di;
  float rs = 0.5f * (rs_n[i] + cs_n);
  rinv[i] = rsqrtf(rs + 0.001f);
  wbuf[i] = rs / (rs + 0.001f);  // rssym * rinv^2
}

// ---------- BxT build + loss term A = sum_i w_i * |x_i|^2 ----------
__global__ __launch_bounds__(256) void k_buildBxT(const float* __restrict__ x,
                                                  const float* __restrict__ d,
                                                  const float* __restrict__ rinv,
                                                  const float* __restrict__ wbuf,
                                                  ushort* __restrict__ BxT,
                                                  float* __restrict__ loss) {
  __shared__ float tile[64][65];
  __shared__ float red[256];
  const int k0 = blockIdx.x * 64, j0 = blockIdx.y * 64;
  const int tc = threadIdx.x & 15, tr = threadIdx.x >> 4;
  float s = 0.f;
#pragma unroll
  for (int it = 0; it < 4; ++it) {
    int r = tr + it * 16;
    float4 v = *(const float4*)&x[(size_t)(k0 + r) * F0 + j0 + tc * 4];
    s += wbuf[k0 + r] * (v.x * v.x + v.y * v.y + v.z * v.z + v.w * v.w);
    tile[r][tc * 4 + 0] = v.x; tile[r][tc * 4 + 1] = v.y;
    tile[r][tc * 4 + 2] = v.z; tile[r][tc * 4 + 3] = v.w;
  }
  red[threadIdx.x] = s;
  __syncthreads();
#pragma unroll
  for (int it = 0; it < 4; ++it) {
    int j = tr + it * 16;
    int kk = tc * 4;
    ushort4 o0, o1;
#pragma unroll
    for (int q = 0; q < 4; ++q) {
      int k = k0 + kk + q;
      float val = tile[kk + q][j];
      ((ushort*)&o0)[q] = f2bf(d[k] * val);
      ((ushort*)&o1)[q] = f2bf(d[k] * rinv[k] * val);
    }
    *(ushort4*)&BxT[(size_t)(j0 + j) * NN + k0 + kk] = o0;
    *(ushort4*)&BxT[(size_t)(F0 + j0 + j) * NN + k0 + kk] = o1;
  }
  __syncthreads();
  for (int off = 128; off > 0; off >>= 1) {
    if (threadIdx.x < off) red[threadIdx.x] += red[threadIdx.x + off];
    __syncthreads();
  }
  if (threadIdx.x == 0) atomicAdd(loss, red[0]);
}

// ---------- W0T[j][k] = bf16(W0[k][j]) ----------
__global__ __launch_bounds__(256) void k_buildW0T(const float* __restrict__ W0,
                                                  ushort* __restrict__ W0T) {
  __shared__ float tile[64][65];
  const int k0 = blockIdx.x * 64, j0 = blockIdx.y * 64;
  const int tc = threadIdx.x & 15, tr = threadIdx.x >> 4;
#pragma unroll
  for (int it = 0; it < 4; ++it) {
    int r = tr + it * 16;
    float4 v = *(const float4*)&W0[(size_t)(k0 + r) * F1 + j0 + tc * 4];
    tile[r][tc * 4 + 0] = v.x; tile[r][tc * 4 + 1] = v.y;
    tile[r][tc * 4 + 2] = v.z; tile[r][tc * 4 + 3] = v.w;
  }
  __syncthreads();
#pragma unroll
  for (int it = 0; it < 4; ++it) {
    int j = tr + it * 16;
    int kk = tc * 4;
    ushort4 o;
#pragma unroll
    for (int q = 0; q < 4; ++q) ((ushort*)&o)[q] = f2bf(tile[kk + q][j]);
    *(ushort4*)&W0T[(size_t)(j0 + j) * F0 + k0 + kk] = o;
  }
}

// ============ 256x256-tile 8-phase MFMA GEMM (T2+T3+T4+T5) ============
// C[8192 x N] = A[8192 x K] @ B[N x K]^T, K = NT*64 per z-slice, bf16 partials out.
// 512 thr = 8 waves (2M x 4N); per-wave C = 128x64 (8x4 frags); BK=64 (2 k-steps).
// LDS 128KB: buf{0,1} x region{A0,A1,B0,B1} x 16KB half-tiles [128 rows][64 cols].
// Swizzle: phys_byte = logical ^ ((row&7)<<4)  (involution; staged via pre-swizzled
// global source + linear gload_lds dest; ds_reads apply same XOR).
template <int NT>
__global__ __launch_bounds__(512, 2) void k_gemm8(
    const ushort* __restrict__ A, const ushort* __restrict__ B,
    ushort* __restrict__ P, int ldn) {
  __shared__ ushort lds[65536];  // 128 KiB
  const int t = threadIdx.x, lane = t & 63, w = t >> 6;
  const int wr = w >> 2, wc = w & 3;
  const int i0 = blockIdx.x * 256, j0 = blockIdx.y * 256;
  const size_t kbase = (size_t)blockIdx.z * (NT * 64);

  // staging source precompute (inverse-swizzled global address, rule #21)
  int srow[2], scol[2];
#pragma unroll
  for (int q = 0; q < 2; ++q) {
    int Pl = q * 8192 + t * 16;                  // physical byte in half-tile
    int L = Pl ^ (((Pl >> 7) & 7) << 4);         // logical byte
    srow[q] = L >> 7;
    scol[q] = (L & 127) >> 1;                    // elements
  }
  const ushort* src[4][2];
#pragma unroll
  for (int q = 0; q < 2; ++q) {
    src[0][q] = A + (size_t)(i0 + srow[q]) * NN + kbase + scol[q];        // A0
    src[1][q] = A + (size_t)(i0 + 128 + srow[q]) * NN + kbase + scol[q];  // A1
    src[2][q] = B + (size_t)(j0 + srow[q]) * NN + kbase + scol[q];        // B0
    src[3][q] = B + (size_t)(j0 + 128 + srow[q]) * NN + kbase + scol[q];  // B1
  }

  auto STAGE = [&](int reg, int tt, int bb) {
    ushort* dstb = &lds[bb * 32768 + reg * 8192 + w * 512];
    gload_lds16(src[reg][0] + tt * 64, dstb);
    gload_lds16(src[reg][1] + tt * 64, dstb + 4096);
  };

  // swizzled read offsets (ushort units)
  const int k0off = ((((lane >> 4) * 16) ^ ((lane & 7) << 4)) >> 1);
  const int k1off = (((64 + (lane >> 4) * 16) ^ ((lane & 7) << 4)) >> 1);
  auto LDA = [&](int bb, int mf, int kk) -> bf16x8 {
    return *(const bf16x8*)&lds[bb * 32768 + wr * 8192 +
                                (mf * 16 + (lane & 15)) * 64 + (kk ? k1off : k0off)];
  };
  auto LDB = [&](int bb, int nf, int kk) -> bf16x8 {
    return *(const bf16x8*)&lds[bb * 32768 + (2 + (wc >> 1)) * 8192 +
                                ((wc & 1) * 64 + nf * 16 + (lane & 15)) * 64 +
                                (kk ? k1off : k0off)];
  };
  auto MM = [&](bf16x8 av, bf16x8 bv, f32x4 c) -> f32x4 {
    return __builtin_amdgcn_mfma_f32_16x16x32_bf16(av, bv, c, 0, 0, 0);
  };

  f32x4 acc[8][4] = {};
  bf16x8 a[4][2], b01[2][2], b23[2][2];

  // prologue: t0 fully -> buf0 (oldest 8 loads), t1 B0,B1 -> buf1
  STAGE(2, 0, 0); STAGE(3, 0, 0); STAGE(0, 0, 0); STAGE(1, 0, 0);
  STAGE(2, 1, 1); STAGE(3, 1, 1);
  asm volatile("s_waitcnt vmcnt(4)" ::: "memory");
  __builtin_amdgcn_sched_barrier(0);
  __builtin_amdgcn_s_barrier();

  constexpr int NIT = NT / 2;
#pragma unroll 1
  for (int i = 0; i < NIT; ++i) {
    const bool nl = (i + 1 < NIT);
    const int tb = 2 * i + 1, t2 = 2 * i + 2, t3 = 2 * i + 3;

    // ---------- phases 1-4: compute tile 2i from buf0 ----------
    // ph1: read A m0-3 + B n0-1; stage A0(tb)->buf1
#pragma unroll
    for (int m = 0; m < 4; ++m) { a[m][0] = LDA(0, m, 0); a[m][1] = LDA(0, m, 1); }
#pragma unroll
    for (int n = 0; n < 2; ++n) { b01[n][0] = LDB(0, n, 0); b01[n][1] = LDB(0, n, 1); }
    STAGE(0, tb, 1);
    __builtin_amdgcn_s_barrier();
    asm volatile("s_waitcnt lgkmcnt(0)" ::: "memory");
    __builtin_amdgcn_sched_barrier(0);
    __builtin_amdgcn_s_setprio(1);
#pragma unroll
    for (int m = 0; m < 4; ++m)
#pragma unroll
      for (int n = 0; n < 2; ++n) {
        acc[m][n] = MM(a[m][0], b01[n][0], acc[m][n]);
        acc[m][n] = MM(a[m][1], b01[n][1], acc[m][n]);
      }
    __builtin_amdgcn_s_setprio(0);
    __builtin_amdgcn_sched_barrier(0);
    __builtin_amdgcn_s_barrier();

    // ph2: read B n2-3; stage A1(tb)->buf1
#pragma unroll
    for (int n = 0; n < 2; ++n) { b23[n][0] = LDB(0, 2 + n, 0); b23[n][1] = LDB(0, 2 + n, 1); }
    STAGE(1, tb, 1);
    __builtin_amdgcn_s_barrier();
    asm volatile("s_waitcnt lgkmcnt(0)" ::: "memory");
    __builtin_amdgcn_sched_barrier(0);
    __builtin_amdgcn_s_setprio(1);
#pragma unroll
    for (int m = 0; m < 4; ++m)
#pragma unroll
      for (int n = 0; n < 2; ++n) {
        acc[m][2 + n] = MM(a[m][0], b23[n][0], acc[m][2 + n]);
        acc[m][2 + n] = MM(a[m][1], b23[n][1], acc[m][2 + n]);
      }
    __builtin_amdgcn_s_setprio(0);
    __builtin_amdgcn_sched_barrier(0);
    __builtin_amdgcn_s_barrier();

    // ph3: read A m4-7; stage B0(t2)->buf0 (B0 last read ph2)
#pragma unroll
    for (int m = 0; m < 4; ++m) { a[m][0] = LDA(0, 4 + m, 0); a[m][1] = LDA(0, 4 + m, 1); }
    if (nl) STAGE(2, t2, 0);
    __builtin_amdgcn_s_barrier();
    asm volatile("s_waitcnt lgkmcnt(0)" ::: "memory");
    __builtin_amdgcn_sched_barrier(0);
    __builtin_amdgcn_s_setprio(1);
#pragma unroll
    for (int m = 0; m < 4; ++m)
#pragma unroll
      for (int n = 0; n < 2; ++n) {
        acc[4 + m][2 + n] = MM(a[m][0], b23[n][0], acc[4 + m][2 + n]);
        acc[4 + m][2 + n] = MM(a[m][1], b23[n][1], acc[4 + m][2 + n]);
      }
    __builtin_amdgcn_s_setprio(0);
    __builtin_amdgcn_sched_barrier(0);
    __builtin_amdgcn_s_barrier();

    // ph4: no reads; stage B1(t2)->buf0; vmcnt checkpoint for tile tb
    if (nl) STAGE(3, t2, 0);
    __builtin_amdgcn_s_barrier();
    __builtin_amdgcn_s_setprio(1);
#pragma unroll
    for (int m = 0; m < 4; ++m)
#pragma unroll
      for (int n = 0; n < 2; ++n) {
        acc[4 + m][n] = MM(a[m][0], b01[n][0], acc[4 + m][n]);
        acc[4 + m][n] = MM(a[m][1], b01[n][1], acc[4 + m][n]);
      }
    __builtin_amdgcn_s_setprio(0);
    if (nl) { asm volatile("s_waitcnt vmcnt(4)" ::: "memory"); }
    else    { asm volatile("s_waitcnt vmcnt(0)" ::: "memory"); }
    __builtin_amdgcn_sched_barrier(0);
    __builtin_amdgcn_s_barrier();

    // ---------- phases 5-8: compute tile 2i+1 from buf1 ----------
    // ph5: read A m0-3 + B n0-1; stage A0(t2)->buf0
#pragma unroll
    for (int m = 0; m < 4; ++m) { a[m][0] = LDA(1, m, 0); a[m][1] = LDA(1, m, 1); }
#pragma unroll
    for (int n = 0; n < 2; ++n) { b01[n][0] = LDB(1, n, 0); b01[n][1] = LDB(1, n, 1); }
    if (nl) STAGE(0, t2, 0);
    __builtin_amdgcn_s_barrier();
    asm volatile("s_waitcnt lgkmcnt(0)" ::: "memory");
    __builtin_amdgcn_sched_barrier(0);
    __builtin_amdgcn_s_setprio(1);
#pragma unroll
    for (int m = 0; m < 4; ++m)
#pragma unroll
      for (int n = 0; n < 2; ++n) {
        acc[m][n] = MM(a[m][0], b01[n][0], acc[m][n]);
        acc[m][n] = MM(a[m][1], b01[n][1], acc[m][n]);
      }
    __builtin_amdgcn_s_setprio(0);
    __builtin_amdgcn_sched_barrier(0);
    __builtin_amdgcn_s_barrier();

    // ph6: read B n2-3; stage A1(t2)->buf0
#pragma unroll
    for (int n = 0; n < 2; ++n) { b23[n][0] = LDB(1, 2 + n, 0); b23[n][1] = LDB(1, 2 + n, 1); }
    if (nl) STAGE(1, t2, 0);
    __builtin_amdgcn_s_barrier();
    asm volatile("s_waitcnt lgkmcnt(0)" ::: "memory");
    __builtin_amdgcn_sched_barrier(0);
    __builtin_amdgcn_s_setprio(1);
#pragma unroll
    for (int m = 0; m < 4; ++m)
#pragma unroll
      for (int n = 0; n < 2; ++n) {
        acc[m][2 + n] = MM(a[m][0], b23[n][0], acc[m][2 + n]);
        acc[m][2 + n] = MM(a[m][1], b23[n][1], acc[m][2 + n]);
      }
    __builtin_amdgcn_s_setprio(0);
    __builtin_amdgcn_sched_barrier(0);
    __builtin_amdgcn_s_barrier();

    // ph7: read A m4-7; stage B0(t3)->buf1 (B0 last read ph6)
#pragma unroll
    for (int m = 0; m < 4; ++m) { a[m][0] = LDA(1, 4 + m, 0); a[m][1] = LDA(1, 4 + m, 1); }
    if (nl) STAGE(2, t3, 1);
    __builtin_amdgcn_s_barrier();
    asm volatile("s_waitcnt lgkmcnt(0)" ::: "memory");
    __builtin_amdgcn_sched_barrier(0);
    __builtin_amdgcn_s_setprio(1);
#pragma unroll
    for (int m = 0; m < 4; ++m)
#pragma unroll
      for (int n = 0; n < 2; ++n) {
        acc[4 + m][2 + n] = MM(a[m][0], b23[n][0], acc[4 + m][2 + n]);
        acc[4 + m][2 + n] = MM(a[m][1], b23[n][1], acc[4 + m][2 + n]);
      }
    __builtin_amdgcn_s_setprio(0);
    __builtin_amdgcn_sched_barrier(0);
    __builtin_amdgcn_s_barrier();

    // ph8: no reads; stage B1(t3)->buf1; vmcnt checkpoint for tile t2
    if (nl) STAGE(3, t3, 1);
    __builtin_amdgcn_s_barrier();
    __builtin_amdgcn_s_setprio(1);
#pragma unroll
    for (int m = 0; m < 4; ++m)
#pragma unroll
      for (int n = 0; n < 2; ++n) {
        acc[4 + m][n] = MM(a[m][0], b01[n][0], acc[4 + m][n]);
        acc[4 + m][n] = MM(a[m][1], b01[n][1], acc[4 + m][n]);
      }
    __builtin_amdgcn_s_setprio(0);
    if (nl) { asm volatile("s_waitcnt vmcnt(4)" ::: "memory"); }
    else    { asm volatile("s_waitcnt vmcnt(0)" ::: "memory"); }
    __builtin_amdgcn_sched_barrier(0);
    __builtin_amdgcn_s_barrier();
  }

  // ---------- epilogue: bf16 partials ----------
  ushort* Pz = P + (size_t)blockIdx.z * NN * ldn;
#pragma unroll
  for (int mf = 0; mf < 8; ++mf) {
    const int rb = i0 + wr * 128 + mf * 16 + (lane >> 4) * 4;
#pragma unroll
    for (int nf = 0; nf < 4; ++nf) {
      const int j = j0 + wc * 64 + nf * 16 + (lane & 15);
      f32x4 v = acc[mf][nf];
#pragma unroll
      for (int q = 0; q < 4; ++q) Pz[(size_t)(rb + q) * ldn + j] = f2bf(v[q]);
    }
  }
}

// ---------- combine mode-0 partials: U1b epilogue + loss term B ----------
__global__ __launch_bounds__(256) void k_combine0(const ushort* __restrict__ P,
                                                  const float* __restrict__ x,
                                                  const float* __restrict__ d,
                                                  const float* __restrict__ rinv,
                                                  ushort* __restrict__ U1b,
                                                  float* __restrict__ loss) {
  __shared__ float red[256];
  float ls = 0.f;
  const int total = NN * 1024 / 8;
  for (int idx = blockIdx.x * 256 + threadIdx.x; idx < total; idx += gridDim.x * 256) {
    const int r = idx >> 7;
    const int c8 = idx & 127;
    uint4 p0 = *(const uint4*)&P[(size_t)r * 1024 + c8 * 8];
    uint4 p1 = *(const uint4*)&P[(size_t)NN * 1024 + (size_t)r * 1024 + c8 * 8];
    float s[8], t[8];
    unpack8(p0, s); unpack8(p1, t);
#pragma unroll
    for (int q = 0; q < 8; ++q) s[q] += t[q];
    const float dr = d[r];
    const int cx = (c8 < 64 ? c8 : c8 - 64) * 8;
    const float4 xv0 = *(const float4*)&x[(size_t)r * F0 + cx];
    const float4 xv1 = *(const float4*)&x[(size_t)r * F0 + cx + 4];
    float xv[8] = {xv0.x, xv0.y, xv0.z, xv0.w, xv1.x, xv1.y, xv1.z, xv1.w};
    if (c8 < 64) {
      ushort4 o0, o1;
#pragma unroll
      for (int q = 0; q < 4; ++q) ((ushort*)&o0)[q] = f2bf(dr * s[q] + dr * dr * xv[q]);
#pragma unroll
      for (int q = 0; q < 4; ++q) ((ushort*)&o1)[q] = f2bf(dr * s[q + 4] + dr * dr * xv[q + 4]);
      *(ushort4*)&U1b[(size_t)r * F0 + cx] = o0;
      *(ushort4*)&U1b[(size_t)r * F0 + cx + 4] = o1;
    } else {
      const float ri = rinv[r];
#pragma unroll
      for (int q = 0; q < 8; ++q) {
        float Y = ri * xv[q];
        float u2 = dr * s[q] + dr * dr * ri * xv[q];
        ls -= Y * u2;
      }
    }
  }
  red[threadIdx.x] = ls;
  __syncthreads();
  for (int off = 128; off > 0; off >>= 1) {
    if (threadIdx.x < off) red[threadIdx.x] += red[threadIdx.x + off];
    __syncthreads();
  }
  if (threadIdx.x == 0) atomicAdd(loss, red[0]);
}

// ---------- mode-1 GEMM with epilogue: H0b = bf16(relu), H0bT = bf16(d*relu)^T ----------
__global__ __launch_bounds__(256) void k_gemm1(const ushort* __restrict__ A,
                                               const ushort* __restrict__ B,
                                               const float* __restrict__ d,
                                               ushort* __restrict__ H0b,
                                               ushort* __restrict__ H0bT) {
  __shared__ ushort As[128 * 32];
  __shared__ ushort Bs[128 * 32];
  const int i0 = blockIdx.x * 128, j0 = blockIdx.y * 128;
  const int t = threadIdx.x;
  const int lane = t & 63, w = t >> 6;
  const int wr = w >> 1, wc = w & 1;
  f32x4 acc[4][4] = {};
  const int e0 = t, e1 = t + 256;
  const ushort* ag0 = A + (size_t)(i0 + (e0 >> 2)) * F0 + (e0 & 3) * 8;
  const ushort* ag1 = A + (size_t)(i0 + (e1 >> 2)) * F0 + (e1 & 3) * 8;
  const ushort* bg0 = B + (size_t)(j0 + (e0 >> 2)) * F0 + (e0 & 3) * 8;
  const ushort* bg1 = B + (size_t)(j0 + (e1 >> 2)) * F0 + (e1 & 3) * 8;
  ushort* la0 = &As[w * 512];
  ushort* la1 = &As[2048 + w * 512];
  ushort* lb0 = &Bs[w * 512];
  ushort* lb1 = &Bs[2048 + w * 512];
  const int abase = (wr * 64 + (lane & 15)) * 32 + (lane >> 4) * 8;
  const int bbase = (wc * 64 + (lane & 15)) * 32 + (lane >> 4) * 8;
  for (int k0 = 0; k0 < F0; k0 += 32) {
    gload_lds16(ag0 + k0, la0);
    gload_lds16(ag1 + k0, la1);
    gload_lds16(bg0 + k0, lb0);
    gload_lds16(bg1 + k0, lb1);
    __syncthreads();
    bf16x8 af[4], bfr[4];
#pragma unroll
    for (int m = 0; m < 4; ++m) af[m] = *(const bf16x8*)&As[abase + m * 512];
#pragma unroll
    for (int n = 0; n < 4; ++n) bfr[n] = *(const bf16x8*)&Bs[bbase + n * 512];
#pragma unroll
    for (int m = 0; m < 4; ++m)
#pragma unroll
      for (int n = 0; n < 4; ++n)
        acc[m][n] = __builtin_amdgcn_mfma_f32_16x16x32_bf16(af[m], bfr[n], acc[m][n], 0, 0, 0);
    __syncthreads();
  }
#pragma unroll
  for (int m = 0; m < 4; ++m) {
    const int rb = i0 + wr * 64 + m * 16 + (lane >> 4) * 4;
#pragma unroll
    for (int n = 0; n < 4; ++n) {
      const int j = j0 + wc * 64 + n * 16 + (lane & 15);
      f32x4 v = acc[m][n];
      ushort4 o;
#pragma unroll
      for (int q = 0; q < 4; ++q) {
        float hv = v[q] > 0.f ? v[q] : 0.f;
        H0b[(size_t)(rb + q) * F1 + j] = f2bf(hv);
        ((ushort*)&o)[q] = f2bf(d[rb + q] * hv);
      }
      *(ushort4*)&H0bT[(size_t)j * NN + rb] = o;
    }
  }
}

// ---------- k_out: combine mode-2 partials into Uh (LDS) then @ W1 ----------
__global__ __launch_bounds__(256) void k_out(const ushort* __restrict__ PH,
                                             const ushort* __restrict__ H0b,
                                             const float* __restrict__ d,
                                             const float* __restrict__ W1,
                                             float* __restrict__ outp) {
  __shared__ float W1s[F1 * F2];
  __shared__ float Uh[16][F1];
  for (int idx = threadIdx.x; idx < F1 * F2; idx += 256) W1s[idx] = W1[idx];
  const int r = threadIdx.x >> 4;
  const int i = blockIdx.x * 16 + r;
  const int c0 = (threadIdx.x & 15) * 16;
  const float di = d[i];
#pragma unroll
  for (int cc = 0; cc < 16; cc += 8) {
    const int c = c0 + cc;
    float s[8] = {};
#pragma unroll
    for (int ks = 0; ks < 8; ++ks) {
      uint4 pv = *(const uint4*)&PH[(size_t)ks * NN * F1 + (size_t)i * F1 + c];
      float t[8]; unpack8(pv, t);
#pragma unroll
      for (int q = 0; q < 8; ++q) s[q] += t[q];
    }
    uint4 hv = *(const uint4*)&H0b[(size_t)i * F1 + c];
    float h[8]; unpack8(hv, h);
#pragma unroll
    for (int q = 0; q < 8; ++q) Uh[r][c + q] = di * s[q] + di * di * h[q];
  }
  __syncthreads();
  const int f = threadIdx.x & 15;
  float acc = 0.f;
#pragma unroll 8
  for (int k = 0; k < F1; ++k) acc += Uh[r][k] * W1s[k * F2 + f];
  outp[(size_t)i * F2 + f] = acc;
}

extern "C" void kernel_launch(void* const* d_in, const int* in_sizes, int n_in,
                              void* d_out, int out_size, void* d_ws, size_t ws_size,
                              hipStream_t stream) {
  const float* x = (const float*)d_in[0];
  const float* adj = (const float*)d_in[1];
  const float* W0 = (const float*)d_in[4];
  const float* W1 = (const float*)d_in[5];
  float* out = (float*)d_out;
  float* loss = out + (size_t)NN * F2;

  float* ws = (float*)d_ws;
  float* d_v = ws;            // 8192
  float* rs_n = ws + 8192;    // 8192
  float* cs = ws + 16384;     // 8192
  float* rinv = ws + 24576;   // 8192
  float* wbuf = ws + 32768;   // 8192
  ushort* adjb = (ushort*)(ws + 65536);              // [8192][8192] bf16
  float* RB = ws + 65536 + (size_t)NN * NN / 2;
  ushort* BxT = (ushort*)RB;                         // [1024][8192] bf16
  ushort* U1b = (ushort*)RB;                         // [8192][512]  bf16 (after BxT dead)
  ushort* H0b = (ushort*)(RB + 2097152);             // [8192][256]  bf16
  ushort* H0bT = (ushort*)(RB + 3145728);            // [256][8192]  bf16
  ushort* W0T = (ushort*)(RB + 4194304);             // [256][512] bf16
  ushort* P = (ushort*)(RB + 4194304 + 32768);       // mode0: [2][8192][1024] bf16
  ushort* PH = P;                                    // mode2: [8][8192][256]  bf16

  hipMemsetAsync(cs, 0, NN * sizeof(float), stream);
  hipMemsetAsync(loss, 0, sizeof(float), stream);

  k_pass1<<<NN, 256, 0, stream>>>(adj, adjb, d_v);
  k_wrowsum<<<NN, 256, 0, stream>>>(adjb, d_v, rs_n);
  k_colsum<<<dim3(NN / 2048, NN / 128), 256, 0, stream>>>(adjb, d_v, cs);
  k_finalize<<<NN / 256, 256, 0, stream>>>(d_v, rs_n, cs, rinv, wbuf);

  k_buildBxT<<<dim3(NN / 64, F0 / 64), 256, 0, stream>>>(x, d_v, rinv, wbuf, BxT, loss);
  k_buildW0T<<<dim3(F0 / 64, F1 / 64), 256, 0, stream>>>(W0, W0T);

  // mode 0: [8192 x 1024] = adjb @ BxT^T, 256^2 8-phase, split-K x2 (K=4096 each)
  k_gemm8<64><<<dim3(NN / 256, 1024 / 256, 2), 512, 0, stream>>>(adjb, BxT, P, 1024);
  k_combine0<<<2048, 256, 0, stream>>>(P, x, d_v, rinv, U1b, loss);

  // mode 1: H0 = relu(U1 @ W0)
  k_gemm1<<<dim3(NN / 128, F1 / 128), 256, 0, stream>>>(U1b, W0T, d_v, H0b, H0bT);

  // mode 2: [8192 x 256] = adjb @ H0bT^T, 256^2 8-phase, split-K x8 (K=1024 each)
  k_gemm8<16><<<dim3(NN / 256, F1 / 256, 8), 512, 0, stream>>>(adjb, H0bT, PH, F1);

  // combine + final GEMM
  k_out<<<NN / 16, 256, 0, stream>>>(PH, H0b, d_v, W1, out);
}

// Round 6
// 387.052 us; speedup vs baseline: 12.5232x; 1.0190x over previous
//
#include <hip/hip_runtime.h>

#define NN 8192
#define F0 512
#define F1 256
#define F2 16

typedef __attribute__((ext_vector_type(8))) short bf16x8;
typedef __attribute__((ext_vector_type(4))) float f32x4;

__device__ __forceinline__ ushort f2bf(float f) {
  unsigned u = __float_as_uint(f);
  u += 0x7FFFu + ((u >> 16) & 1u);  // RNE
  return (ushort)(u >> 16);
}
__device__ __forceinline__ float bf2f(ushort u) {
  return __uint_as_float(((unsigned)u) << 16);
}
__device__ __forceinline__ void unpack8(uint4 a, float* f) {
  f[0] = bf2f((ushort)(a.x & 0xffff)); f[1] = bf2f((ushort)(a.x >> 16));
  f[2] = bf2f((ushort)(a.y & 0xffff)); f[3] = bf2f((ushort)(a.y >> 16));
  f[4] = bf2f((ushort)(a.z & 0xffff)); f[5] = bf2f((ushort)(a.z >> 16));
  f[6] = bf2f((ushort)(a.w & 0xffff)); f[7] = bf2f((ushort)(a.w >> 16));
}
__device__ __forceinline__ void gload_lds16(const ushort* g, ushort* l) {
  __builtin_amdgcn_global_load_lds((const __attribute__((address_space(1))) void*)g,
                                   (__attribute__((address_space(3))) void*)l, 16, 0, 0);
}

// ---------- pass1: rowsum (fp32 exact) + adj -> bf16 ----------
__global__ __launch_bounds__(256) void k_pass1(const float* __restrict__ adj,
                                               ushort* __restrict__ adjb,
                                               float* __restrict__ d) {
  __shared__ float red[256];
  const size_t base = (size_t)blockIdx.x * NN;
  float s = 0.f;
  for (int j = threadIdx.x * 4; j < NN; j += 1024) {
    float4 v = *(const float4*)&adj[base + j];
    s += (v.x + v.y) + (v.z + v.w);
    ushort4 o;
    o.x = f2bf(v.x); o.y = f2bf(v.y); o.z = f2bf(v.z); o.w = f2bf(v.w);
    *(ushort4*)&adjb[base + j] = o;
  }
  red[threadIdx.x] = s;
  __syncthreads();
  for (int off = 128; off > 0; off >>= 1) {
    if (threadIdx.x < off) red[threadIdx.x] += red[threadIdx.x + off];
    __syncthreads();
  }
  if (threadIdx.x == 0) d[blockIdx.x] = rsqrtf(1.0f + red[0]);
}

// ---------- rs_n[i] = d_i * sum_j adjb[i][j] d_j + d_i^2 ----------
__global__ __launch_bounds__(256) void k_wrowsum(const ushort* __restrict__ adjb,
                                                 const float* __restrict__ d,
                                                 float* __restrict__ rs_n) {
  __shared__ float red[256];
  float s = 0.f;
  for (int p = threadIdx.x; p < NN / 8; p += 256) {
    uint4 pk = *(const uint4*)&adjb[(size_t)blockIdx.x * NN + p * 8];
    float t[8]; unpack8(pk, t);
    const float4 d0 = *(const float4*)&d[p * 8];
    const float4 d1 = *(const float4*)&d[p * 8 + 4];
    s += t[0] * d0.x + t[1] * d0.y + t[2] * d0.z + t[3] * d0.w
       + t[4] * d1.x + t[5] * d1.y + t[6] * d1.z + t[7] * d1.w;
  }
  red[threadIdx.x] = s;
  __syncthreads();
  for (int off = 128; off > 0; off >>= 1) {
    if (threadIdx.x < off) red[threadIdx.x] += red[threadIdx.x + off];
    __syncthreads();
  }
  if (threadIdx.x == 0) {
    float di = d[blockIdx.x];
    rs_n[blockIdx.x] = di * red[0] + di * di;
  }
}

// ---------- cs_raw[c] += sum_i adjb[i][c] d_i ----------
__global__ __launch_bounds__(256) void k_colsum(const ushort* __restrict__ adjb,
                                                const float* __restrict__ d,
                                                float* __restrict__ cs) {
  const int c0 = blockIdx.x * 2048 + threadIdx.x * 8;
  const int r0 = blockIdx.y * 128;
  float acc[8] = {};
  for (int i = 0; i < 128; ++i) {
    uint4 v = *(const uint4*)&adjb[(size_t)(r0 + i) * NN + c0];
    float t[8]; unpack8(v, t);
    float di = d[r0 + i];
#pragma unroll
    for (int q = 0; q < 8; ++q) acc[q] += t[q] * di;
  }
#pragma unroll
  for (int q = 0; q < 8; ++q) atomicAdd(&cs[c0 + q], acc[q]);
}

__global__ __launch_bounds__(256) void k_finalize(const float* __restrict__ d,
                                                  const float* __restrict__ rs_n,
                                                  const float* __restrict__ cs_raw,
                                                  float* __restrict__ rinv,
                                                  float* __restrict__ wbuf) {
  int i = blockIdx.x * 256 + threadIdx.x;
  float di = d[i];
  float cs_n = di * cs_raw[i] + di * di;
  float rs = 0.5f * (rs_n[i] + cs_n);
  rinv[i] = rsqrtf(rs + 0.001f);
  wbuf[i] = rs / (rs + 0.001f);  // rssym * rinv^2
}

// ---------- BxT build + loss term A = sum_i w_i * |x_i|^2 ----------
__global__ __launch_bounds__(256) void k_buildBxT(const float* __restrict__ x,
                                                  const float* __restrict__ d,
                                                  const float* __restrict__ rinv,
                                                  const float* __restrict__ wbuf,
                                                  ushort* __restrict__ BxT,
                                                  float* __restrict__ loss) {
  __shared__ float tile[64][65];
  __shared__ float red[256];
  const int k0 = blockIdx.x * 64, j0 = blockIdx.y * 64;
  const int tc = threadIdx.x & 15, tr = threadIdx.x >> 4;
  float s = 0.f;
#pragma unroll
  for (int it = 0; it < 4; ++it) {
    int r = tr + it * 16;
    float4 v = *(const float4*)&x[(size_t)(k0 + r) * F0 + j0 + tc * 4];
    s += wbuf[k0 + r] * (v.x * v.x + v.y * v.y + v.z * v.z + v.w * v.w);
    tile[r][tc * 4 + 0] = v.x; tile[r][tc * 4 + 1] = v.y;
    tile[r][tc * 4 + 2] = v.z; tile[r][tc * 4 + 3] = v.w;
  }
  red[threadIdx.x] = s;
  __syncthreads();
#pragma unroll
  for (int it = 0; it < 4; ++it) {
    int j = tr + it * 16;
    int kk = tc * 4;
    ushort4 o0, o1;
#pragma unroll
    for (int q = 0; q < 4; ++q) {
      int k = k0 + kk + q;
      float val = tile[kk + q][j];
      ((ushort*)&o0)[q] = f2bf(d[k] * val);
      ((ushort*)&o1)[q] = f2bf(d[k] * rinv[k] * val);
    }
    *(ushort4*)&BxT[(size_t)(j0 + j) * NN + k0 + kk] = o0;
    *(ushort4*)&BxT[(size_t)(F0 + j0 + j) * NN + k0 + kk] = o1;
  }
  __syncthreads();
  for (int off = 128; off > 0; off >>= 1) {
    if (threadIdx.x < off) red[threadIdx.x] += red[threadIdx.x + off];
    __syncthreads();
  }
  if (threadIdx.x == 0) atomicAdd(loss, red[0]);
}

// ---------- W0T[j][k] = bf16(W0[k][j]) ----------
__global__ __launch_bounds__(256) void k_buildW0T(const float* __restrict__ W0,
                                                  ushort* __restrict__ W0T) {
  __shared__ float tile[64][65];
  const int k0 = blockIdx.x * 64, j0 = blockIdx.y * 64;
  const int tc = threadIdx.x & 15, tr = threadIdx.x >> 4;
#pragma unroll
  for (int it = 0; it < 4; ++it) {
    int r = tr + it * 16;
    float4 v = *(const float4*)&W0[(size_t)(k0 + r) * F1 + j0 + tc * 4];
    tile[r][tc * 4 + 0] = v.x; tile[r][tc * 4 + 1] = v.y;
    tile[r][tc * 4 + 2] = v.z; tile[r][tc * 4 + 3] = v.w;
  }
  __syncthreads();
#pragma unroll
  for (int it = 0; it < 4; ++it) {
    int j = tr + it * 16;
    int kk = tc * 4;
    ushort4 o;
#pragma unroll
    for (int q = 0; q < 4; ++q) ((ushort*)&o)[q] = f2bf(tile[kk + q][j]);
    *(ushort4*)&W0T[(size_t)(j0 + j) * F0 + k0 + kk] = o;
  }
}

// ============ 256x256-tile 8-phase MFMA GEMM (T2+T3+T4+T5) ============
// C[8192 x N] = A[8192 x K] @ B[N x K]^T, K = NT*64 per z-slice, bf16 partials out.
// 512 thr = 8 waves (2M x 4N); per-wave C = 128x64 (8x4 frags); BK=64 (2 k-steps).
// LDS 128KB: buf{0,1} x region{A0,A1,B0,B1} x 16KB half-tiles [128 rows][64 cols].
// Swizzle: phys_byte = logical ^ ((row&7)<<4)  (involution; staged via pre-swizzled
// global source + linear gload_lds dest; ds_reads apply same XOR).
template <int NT>
__global__ __launch_bounds__(512, 2) void k_gemm8(
    const ushort* __restrict__ A, const ushort* __restrict__ B,
    ushort* __restrict__ P, int ldn) {
  __shared__ ushort lds[65536];  // 128 KiB
  const int t = threadIdx.x, lane = t & 63, w = t >> 6;
  const int wr = w >> 2, wc = w & 3;
  const int i0 = blockIdx.x * 256, j0 = blockIdx.y * 256;
  const size_t kbase = (size_t)blockIdx.z * (NT * 64);

  // staging source precompute (inverse-swizzled global address, rule #21)
  int srow[2], scol[2];
#pragma unroll
  for (int q = 0; q < 2; ++q) {
    int Pl = q * 8192 + t * 16;                  // physical byte in half-tile
    int L = Pl ^ (((Pl >> 7) & 7) << 4);         // logical byte
    srow[q] = L >> 7;
    scol[q] = (L & 127) >> 1;                    // elements
  }
  const ushort* src[4][2];
#pragma unroll
  for (int q = 0; q < 2; ++q) {
    src[0][q] = A + (size_t)(i0 + srow[q]) * NN + kbase + scol[q];        // A0
    src[1][q] = A + (size_t)(i0 + 128 + srow[q]) * NN + kbase + scol[q];  // A1
    src[2][q] = B + (size_t)(j0 + srow[q]) * NN + kbase + scol[q];        // B0
    src[3][q] = B + (size_t)(j0 + 128 + srow[q]) * NN + kbase + scol[q];  // B1
  }

  auto STAGE = [&](int reg, int tt, int bb) {
    ushort* dstb = &lds[bb * 32768 + reg * 8192 + w * 512];
    gload_lds16(src[reg][0] + tt * 64, dstb);
    gload_lds16(src[reg][1] + tt * 64, dstb + 4096);
  };

  // swizzled read offsets (ushort units)
  const int k0off = ((((lane >> 4) * 16) ^ ((lane & 7) << 4)) >> 1);
  const int k1off = (((64 + (lane >> 4) * 16) ^ ((lane & 7) << 4)) >> 1);
  auto LDA = [&](int bb, int mf, int kk) -> bf16x8 {
    return *(const bf16x8*)&lds[bb * 32768 + wr * 8192 +
                                (mf * 16 + (lane & 15)) * 64 + (kk ? k1off : k0off)];
  };
  auto LDB = [&](int bb, int nf, int kk) -> bf16x8 {
    return *(const bf16x8*)&lds[bb * 32768 + (2 + (wc >> 1)) * 8192 +
                                ((wc & 1) * 64 + nf * 16 + (lane & 15)) * 64 +
                                (kk ? k1off : k0off)];
  };
  auto MM = [&](bf16x8 av, bf16x8 bv, f32x4 c) -> f32x4 {
    return __builtin_amdgcn_mfma_f32_16x16x32_bf16(av, bv, c, 0, 0, 0);
  };

  f32x4 acc[8][4] = {};
  bf16x8 a[4][2], b01[2][2], b23[2][2];

  // prologue: t0 fully -> buf0 (oldest 8 loads), t1 B0,B1 -> buf1
  STAGE(2, 0, 0); STAGE(3, 0, 0); STAGE(0, 0, 0); STAGE(1, 0, 0);
  STAGE(2, 1, 1); STAGE(3, 1, 1);
  asm volatile("s_waitcnt vmcnt(4)" ::: "memory");
  __builtin_amdgcn_sched_barrier(0);
  __builtin_amdgcn_s_barrier();

  constexpr int NIT = NT / 2;
#pragma unroll 1
  for (int i = 0; i < NIT; ++i) {
    const bool nl = (i + 1 < NIT);
    const int tb = 2 * i + 1, t2 = 2 * i + 2, t3 = 2 * i + 3;

    // ---------- phases 1-4: compute tile 2i from buf0 ----------
    // ph1: read A m0-3 + B n0-1; stage A0(tb)->buf1
#pragma unroll
    for (int m = 0; m < 4; ++m) { a[m][0] = LDA(0, m, 0); a[m][1] = LDA(0, m, 1); }
#pragma unroll
    for (int n = 0; n < 2; ++n) { b01[n][0] = LDB(0, n, 0); b01[n][1] = LDB(0, n, 1); }
    STAGE(0, tb, 1);
    __builtin_amdgcn_s_barrier();
    asm volatile("s_waitcnt lgkmcnt(0)" ::: "memory");
    __builtin_amdgcn_sched_barrier(0);
    __builtin_amdgcn_s_setprio(1);
#pragma unroll
    for (int m = 0; m < 4; ++m)
#pragma unroll
      for (int n = 0; n < 2; ++n) {
        acc[m][n] = MM(a[m][0], b01[n][0], acc[m][n]);
        acc[m][n] = MM(a[m][1], b01[n][1], acc[m][n]);
      }
    __builtin_amdgcn_s_setprio(0);
    __builtin_amdgcn_sched_barrier(0);
    __builtin_amdgcn_s_barrier();

    // ph2: read B n2-3; stage A1(tb)->buf1
#pragma unroll
    for (int n = 0; n < 2; ++n) { b23[n][0] = LDB(0, 2 + n, 0); b23[n][1] = LDB(0, 2 + n, 1); }
    STAGE(1, tb, 1);
    __builtin_amdgcn_s_barrier();
    asm volatile("s_waitcnt lgkmcnt(0)" ::: "memory");
    __builtin_amdgcn_sched_barrier(0);
    __builtin_amdgcn_s_setprio(1);
#pragma unroll
    for (int m = 0; m < 4; ++m)
#pragma unroll
      for (int n = 0; n < 2; ++n) {
        acc[m][2 + n] = MM(a[m][0], b23[n][0], acc[m][2 + n]);
        acc[m][2 + n] = MM(a[m][1], b23[n][1], acc[m][2 + n]);
      }
    __builtin_amdgcn_s_setprio(0);
    __builtin_amdgcn_sched_barrier(0);
    __builtin_amdgcn_s_barrier();

    // ph3: read A m4-7; stage B0(t2)->buf0 (B0 last read ph2)
#pragma unroll
    for (int m = 0; m < 4; ++m) { a[m][0] = LDA(0, 4 + m, 0); a[m][1] = LDA(0, 4 + m, 1); }
    if (nl) STAGE(2, t2, 0);
    __builtin_amdgcn_s_barrier();
    asm volatile("s_waitcnt lgkmcnt(0)" ::: "memory");
    __builtin_amdgcn_sched_barrier(0);
    __builtin_amdgcn_s_setprio(1);
#pragma unroll
    for (int m = 0; m < 4; ++m)
#pragma unroll
      for (int n = 0; n < 2; ++n) {
        acc[4 + m][2 + n] = MM(a[m][0], b23[n][0], acc[4 + m][2 + n]);
        acc[4 + m][2 + n] = MM(a[m][1], b23[n][1], acc[4 + m][2 + n]);
      }
    __builtin_amdgcn_s_setprio(0);
    __builtin_amdgcn_sched_barrier(0);
    __builtin_amdgcn_s_barrier();

    // ph4: no reads; stage B1(t2)->buf0; vmcnt checkpoint for tile tb
    if (nl) STAGE(3, t2, 0);
    __builtin_amdgcn_s_barrier();
    __builtin_amdgcn_s_setprio(1);
#pragma unroll
    for (int m = 0; m < 4; ++m)
#pragma unroll
      for (int n = 0; n < 2; ++n) {
        acc[4 + m][n] = MM(a[m][0], b01[n][0], acc[4 + m][n]);
        acc[4 + m][n] = MM(a[m][1], b01[n][1], acc[4 + m][n]);
      }
    __builtin_amdgcn_s_setprio(0);
    if (nl) { asm volatile("s_waitcnt vmcnt(4)" ::: "memory"); }
    else    { asm volatile("s_waitcnt vmcnt(0)" ::: "memory"); }
    __builtin_amdgcn_sched_barrier(0);
    __builtin_amdgcn_s_barrier();

    // ---------- phases 5-8: compute tile 2i+1 from buf1 ----------
    // ph5: read A m0-3 + B n0-1; stage A0(t2)->buf0
#pragma unroll
    for (int m = 0; m < 4; ++m) { a[m][0] = LDA(1, m, 0); a[m][1] = LDA(1, m, 1); }
#pragma unroll
    for (int n = 0; n < 2; ++n) { b01[n][0] = LDB(1, n, 0); b01[n][1] = LDB(1, n, 1); }
    if (nl) STAGE(0, t2, 0);
    __builtin_amdgcn_s_barrier();
    asm volatile("s_waitcnt lgkmcnt(0)" ::: "memory");
    __builtin_amdgcn_sched_barrier(0);
    __builtin_amdgcn_s_setprio(1);
#pragma unroll
    for (int m = 0; m < 4; ++m)
#pragma unroll
      for (int n = 0; n < 2; ++n) {
        acc[m][n] = MM(a[m][0], b01[n][0], acc[m][n]);
        acc[m][n] = MM(a[m][1], b01[n][1], acc[m][n]);
      }
    __builtin_amdgcn_s_setprio(0);
    __builtin_amdgcn_sched_barrier(0);
    __builtin_amdgcn_s_barrier();

    // ph6: read B n2-3; stage A1(t2)->buf0
#pragma unroll
    for (int n = 0; n < 2; ++n) { b23[n][0] = LDB(1, 2 + n, 0); b23[n][1] = LDB(1, 2 + n, 1); }
    if (nl) STAGE(1, t2, 0);
    __builtin_amdgcn_s_barrier();
    asm volatile("s_waitcnt lgkmcnt(0)" ::: "memory");
    __builtin_amdgcn_sched_barrier(0);
    __builtin_amdgcn_s_setprio(1);
#pragma unroll
    for (int m = 0; m < 4; ++m)
#pragma unroll
      for (int n = 0; n < 2; ++n) {
        acc[m][2 + n] = MM(a[m][0], b23[n][0], acc[m][2 + n]);
        acc[m][2 + n] = MM(a[m][1], b23[n][1], acc[m][2 + n]);
      }
    __builtin_amdgcn_s_setprio(0);
    __builtin_amdgcn_sched_barrier(0);
    __builtin_amdgcn_s_barrier();

    // ph7: read A m4-7; stage B0(t3)->buf1 (B0 last read ph6)
#pragma unroll
    for (int m = 0; m < 4; ++m) { a[m][0] = LDA(1, 4 + m, 0); a[m][1] = LDA(1, 4 + m, 1); }
    if (nl) STAGE(2, t3, 1);
    __builtin_amdgcn_s_barrier();
    asm volatile("s_waitcnt lgkmcnt(0)" ::: "memory");
    __builtin_amdgcn_sched_barrier(0);
    __builtin_amdgcn_s_setprio(1);
#pragma unroll
    for (int m = 0; m < 4; ++m)
#pragma unroll
      for (int n = 0; n < 2; ++n) {
        acc[4 + m][2 + n] = MM(a[m][0], b23[n][0], acc[4 + m][2 + n]);
        acc[4 + m][2 + n] = MM(a[m][1], b23[n][1], acc[4 + m][2 + n]);
      }
    __builtin_amdgcn_s_setprio(0);
    __builtin_amdgcn_sched_barrier(0);
    __builtin_amdgcn_s_barrier();

    // ph8: no reads; stage B1(t3)->buf1; vmcnt checkpoint for tile t2
    if (nl) STAGE(3, t3, 1);
    __builtin_amdgcn_s_barrier();
    __builtin_amdgcn_s_setprio(1);
#pragma unroll
    for (int m = 0; m < 4; ++m)
#pragma unroll
      for (int n = 0; n < 2; ++n) {
        acc[4 + m][n] = MM(a[m][0], b01[n][0], acc[4 + m][n]);
        acc[4 + m][n] = MM(a[m][1], b01[n][1], acc[4 + m][n]);
      }
    __builtin_amdgcn_s_setprio(0);
    if (nl) { asm volatile("s_waitcnt vmcnt(4)" ::: "memory"); }
    else    { asm volatile("s_waitcnt vmcnt(0)" ::: "memory"); }
    __builtin_amdgcn_sched_barrier(0);
    __builtin_amdgcn_s_barrier();
  }

  // ---------- epilogue: bf16 partials ----------
  ushort* Pz = P + (size_t)blockIdx.z * NN * ldn;
#pragma unroll
  for (int mf = 0; mf < 8; ++mf) {
    const int rb = i0 + wr * 128 + mf * 16 + (lane >> 4) * 4;
#pragma unroll
    for (int nf = 0; nf < 4; ++nf) {
      const int j = j0 + wc * 64 + nf * 16 + (lane & 15);
      f32x4 v = acc[mf][nf];
#pragma unroll
      for (int q = 0; q < 4; ++q) Pz[(size_t)(rb + q) * ldn + j] = f2bf(v[q]);
    }
  }
}

// ---------- combine mode-0 partials: U1b epilogue + loss term B ----------
__global__ __launch_bounds__(256) void k_combine0(const ushort* __restrict__ P,
                                                  const float* __restrict__ x,
                                                  const float* __restrict__ d,
                                                  const float* __restrict__ rinv,
                                                  ushort* __restrict__ U1b,
                                                  float* __restrict__ loss) {
  __shared__ float red[256];
  float ls = 0.f;
  const int total = NN * 1024 / 8;
  for (int idx = blockIdx.x * 256 + threadIdx.x; idx < total; idx += gridDim.x * 256) {
    const int r = idx >> 7;
    const int c8 = idx & 127;
    uint4 p0 = *(const uint4*)&P[(size_t)r * 1024 + c8 * 8];
    uint4 p1 = *(const uint4*)&P[(size_t)NN * 1024 + (size_t)r * 1024 + c8 * 8];
    float s[8], t[8];
    unpack8(p0, s); unpack8(p1, t);
#pragma unroll
    for (int q = 0; q < 8; ++q) s[q] += t[q];
    const float dr = d[r];
    const int cx = (c8 < 64 ? c8 : c8 - 64) * 8;
    const float4 xv0 = *(const float4*)&x[(size_t)r * F0 + cx];
    const float4 xv1 = *(const float4*)&x[(size_t)r * F0 + cx + 4];
    float xv[8] = {xv0.x, xv0.y, xv0.z, xv0.w, xv1.x, xv1.y, xv1.z, xv1.w};
    if (c8 < 64) {
      ushort4 o0, o1;
#pragma unroll
      for (int q = 0; q < 4; ++q) ((ushort*)&o0)[q] = f2bf(dr * s[q] + dr * dr * xv[q]);
#pragma unroll
      for (int q = 0; q < 4; ++q) ((ushort*)&o1)[q] = f2bf(dr * s[q + 4] + dr * dr * xv[q + 4]);
      *(ushort4*)&U1b[(size_t)r * F0 + cx] = o0;
      *(ushort4*)&U1b[(size_t)r * F0 + cx + 4] = o1;
    } else {
      const float ri = rinv[r];
#pragma unroll
      for (int q = 0; q < 8; ++q) {
        float Y = ri * xv[q];
        float u2 = dr * s[q] + dr * dr * ri * xv[q];
        ls -= Y * u2;
      }
    }
  }
  red[threadIdx.x] = ls;
  __syncthreads();
  for (int off = 128; off > 0; off >>= 1) {
    if (threadIdx.x < off) red[threadIdx.x] += red[threadIdx.x + off];
    __syncthreads();
  }
  if (threadIdx.x == 0) atomicAdd(loss, red[0]);
}

// ---------- mode-1 GEMM with epilogue: H0b = bf16(relu), H0bT = bf16(d*relu)^T ----------
__global__ __launch_bounds__(256) void k_gemm1(const ushort* __restrict__ A,
                                               const ushort* __restrict__ B,
                                               const float* __restrict__ d,
                                               ushort* __restrict__ H0b,
                                               ushort* __restrict__ H0bT) {
  __shared__ ushort As[128 * 32];
  __shared__ ushort Bs[128 * 32];
  const int i0 = blockIdx.x * 128, j0 = blockIdx.y * 128;
  const int t = threadIdx.x;
  const int lane = t & 63, w = t >> 6;
  const int wr = w >> 1, wc = w & 1;
  f32x4 acc[4][4] = {};
  const int e0 = t, e1 = t + 256;
  const ushort* ag0 = A + (size_t)(i0 + (e0 >> 2)) * F0 + (e0 & 3) * 8;
  const ushort* ag1 = A + (size_t)(i0 + (e1 >> 2)) * F0 + (e1 & 3) * 8;
  const ushort* bg0 = B + (size_t)(j0 + (e0 >> 2)) * F0 + (e0 & 3) * 8;
  const ushort* bg1 = B + (size_t)(j0 + (e1 >> 2)) * F0 + (e1 & 3) * 8;
  ushort* la0 = &As[w * 512];
  ushort* la1 = &As[2048 + w * 512];
  ushort* lb0 = &Bs[w * 512];
  ushort* lb1 = &Bs[2048 + w * 512];
  const int abase = (wr * 64 + (lane & 15)) * 32 + (lane >> 4) * 8;
  const int bbase = (wc * 64 + (lane & 15)) * 32 + (lane >> 4) * 8;
  for (int k0 = 0; k0 < F0; k0 += 32) {
    gload_lds16(ag0 + k0, la0);
    gload_lds16(ag1 + k0, la1);
    gload_lds16(bg0 + k0, lb0);
    gload_lds16(bg1 + k0, lb1);
    __syncthreads();
    bf16x8 af[4], bfr[4];
#pragma unroll
    for (int m = 0; m < 4; ++m) af[m] = *(const bf16x8*)&As[abase + m * 512];
#pragma unroll
    for (int n = 0; n < 4; ++n) bfr[n] = *(const bf16x8*)&Bs[bbase + n * 512];
#pragma unroll
    for (int m = 0; m < 4; ++m)
#pragma unroll
      for (int n = 0; n < 4; ++n)
        acc[m][n] = __builtin_amdgcn_mfma_f32_16x16x32_bf16(af[m], bfr[n], acc[m][n], 0, 0, 0);
    __syncthreads();
  }
#pragma unroll
  for (int m = 0; m < 4; ++m) {
    const int rb = i0 + wr * 64 + m * 16 + (lane >> 4) * 4;
#pragma unroll
    for (int n = 0; n < 4; ++n) {
      const int j = j0 + wc * 64 + n * 16 + (lane & 15);
      f32x4 v = acc[m][n];
      ushort4 o;
#pragma unroll
      for (int q = 0; q < 4; ++q) {
        float hv = v[q] > 0.f ? v[q] : 0.f;
        H0b[(size_t)(rb + q) * F1 + j] = f2bf(hv);
        ((ushort*)&o)[q] = f2bf(d[rb + q] * hv);
      }
      *(ushort4*)&H0bT[(size_t)j * NN + rb] = o;
    }
  }
}

// ---------- k_out: combine mode-2 partials into Uh (LDS) then @ W1 ----------
__global__ __launch_bounds__(256) void k_out(const ushort* __restrict__ PH,
                                             const ushort* __restrict__ H0b,
                                             const float* __restrict__ d,
                                             const float* __restrict__ W1,
                                             float* __restrict__ outp) {
  __shared__ float W1s[F1 * F2];
  __shared__ float Uh[16][F1];
  for (int idx = threadIdx.x; idx < F1 * F2; idx += 256) W1s[idx] = W1[idx];
  const int r = threadIdx.x >> 4;
  const int i = blockIdx.x * 16 + r;
  const int c0 = (threadIdx.x & 15) * 16;
  const float di = d[i];
#pragma unroll
  for (int cc = 0; cc < 16; cc += 8) {
    const int c = c0 + cc;
    float s[8] = {};
#pragma unroll
    for (int ks = 0; ks < 8; ++ks) {
      uint4 pv = *(const uint4*)&PH[(size_t)ks * NN * F1 + (size_t)i * F1 + c];
      float t[8]; unpack8(pv, t);
#pragma unroll
      for (int q = 0; q < 8; ++q) s[q] += t[q];
    }
    uint4 hv = *(const uint4*)&H0b[(size_t)i * F1 + c];
    float h[8]; unpack8(hv, h);
#pragma unroll
    for (int q = 0; q < 8; ++q) Uh[r][c + q] = di * s[q] + di * di * h[q];
  }
  __syncthreads();
  const int f = threadIdx.x & 15;
  float acc = 0.f;
#pragma unroll 8
  for (int k = 0; k < F1; ++k) acc += Uh[r][k] * W1s[k * F2 + f];
  outp[(size_t)i * F2 + f] = acc;
}

extern "C" void kernel_launch(void* const* d_in, const int* in_sizes, int n_in,
                              void* d_out, int out_size, void* d_ws, size_t ws_size,
                              hipStream_t stream) {
  const float* x = (const float*)d_in[0];
  const float* adj = (const float*)d_in[1];
  const float* W0 = (const float*)d_in[4];
  const float* W1 = (const float*)d_in[5];
  float* out = (float*)d_out;
  float* loss = out + (size_t)NN * F2;

  float* ws = (float*)d_ws;
  float* d_v = ws;            // 8192
  float* rs_n = ws + 8192;    // 8192
  float* cs = ws + 16384;     // 8192
  float* rinv = ws + 24576;   // 8192
  float* wbuf = ws + 32768;   // 8192
  ushort* adjb = (ushort*)(ws + 65536);              // [8192][8192] bf16
  float* RB = ws + 65536 + (size_t)NN * NN / 2;
  ushort* BxT = (ushort*)RB;                         // [1024][8192] bf16
  ushort* U1b = (ushort*)RB;                         // [8192][512]  bf16 (after BxT dead)
  ushort* H0b = (ushort*)(RB + 2097152);             // [8192][256]  bf16
  ushort* H0bT = (ushort*)(RB + 3145728);            // [256][8192]  bf16
  ushort* W0T = (ushort*)(RB + 4194304);             // [256][512] bf16
  ushort* P = (ushort*)(RB + 4194304 + 32768);       // mode0: [2][8192][1024] bf16
  ushort* PH = P;                                    // mode2: [8][8192][256]  bf16

  hipMemsetAsync(cs, 0, NN * sizeof(float), stream);
  hipMemsetAsync(loss, 0, sizeof(float), stream);

  k_pass1<<<NN, 256, 0, stream>>>(adj, adjb, d_v);
  k_wrowsum<<<NN, 256, 0, stream>>>(adjb, d_v, rs_n);
  k_colsum<<<dim3(NN / 2048, NN / 128), 256, 0, stream>>>(adjb, d_v, cs);
  k_finalize<<<NN / 256, 256, 0, stream>>>(d_v, rs_n, cs, rinv, wbuf);

  k_buildBxT<<<dim3(NN / 64, F0 / 64), 256, 0, stream>>>(x, d_v, rinv, wbuf, BxT, loss);
  k_buildW0T<<<dim3(F0 / 64, F1 / 64), 256, 0, stream>>>(W0, W0T);

  // mode 0: [8192 x 1024] = adjb @ BxT^T, 256^2 8-phase, split-K x2 (K=4096 each)
  k_gemm8<64><<<dim3(NN / 256, 1024 / 256, 2), 512, 0, stream>>>(adjb, BxT, P, 1024);
  k_combine0<<<2048, 256, 0, stream>>>(P, x, d_v, rinv, U1b, loss);

  // mode 1: H0 = relu(U1 @ W0)
  k_gemm1<<<dim3(NN / 128, F1 / 128), 256, 0, stream>>>(U1b, W0T, d_v, H0b, H0bT);

  // mode 2: [8192 x 256] = adjb @ H0bT^T, 256^2 8-phase, split-K x8 (K=1024 each)
  k_gemm8<16><<<dim3(NN / 256, F1 / 256, 8), 512, 0, stream>>>(adjb, H0bT, PH, F1);

  // combine + final GEMM
  k_out<<<NN / 16, 256, 0, stream>>>(PH, H0b, d_v, W1, out);
}